// Round 2
// baseline (511.347 us; speedup 1.0000x reference)
//
#include <hip/hip_runtime.h>
#include <hip/hip_bf16.h>

#define NN 1024
#define DD 64
#define EE 16384
#define PP 8192
#define EPSF 1e-5f

typedef __hip_bfloat16 bf16;

static __device__ __forceinline__ float b2f(bf16 v) { return __bfloat162float(v); }

// ---------------- dtype probe: detect fp32-vs-bf16 float inputs ----------------
// Read the emb buffer as bf16 halfwords. If the underlying data is fp32, the
// low-16-bit halves decode to bf16 with random exponents -> |v|>1e3 or NaN
// somewhere (p ~ 0.46 per sample, thousands of samples). True bf16 N(0,0.1)
// never exceeds ~0.5.
__global__ void k_probe(const unsigned short* __restrict__ raw, int n, int* __restrict__ flag) {
    int i = blockIdx.x * blockDim.x + threadIdx.x;
    if (i >= n) return;
    unsigned int bits = ((unsigned int)raw[i]) << 16;
    float v = __uint_as_float(bits);
    if (!(fabsf(v) <= 1e3f)) atomicOr(flag, 1);  // catches >1e3, inf, NaN
}

// decode a float input (bf16 or fp32 per flag) into fp32 workspace
__global__ void k_decode(const void* __restrict__ src, float* __restrict__ dst, int n,
                         const int* __restrict__ flag) {
    int i = blockIdx.x * blockDim.x + threadIdx.x;
    if (i >= n) return;
    if (*flag) {
        dst[i] = ((const float*)src)[i];
    } else {
        dst[i] = b2f(((const bf16*)src)[i]);
    }
}

// ---------------- degree + edge-indicator bitmap ----------------
__global__ void k_deg_eim(const int* __restrict__ ei, int* __restrict__ deg,
                          unsigned int* __restrict__ eim) {
    int e = blockIdx.x * blockDim.x + threadIdx.x;
    if (e >= EE) return;
    int s = ei[e];
    int d = ei[EE + e];
    atomicAdd(&deg[d], 1);
    unsigned int idx = (unsigned int)(s * NN + d);
    atomicOr(&eim[idx >> 5], 1u << (idx & 31));
}

// ---------------- embedding gather (from decoded fp32 emb) ----------------
__global__ void k_embed(const int* __restrict__ x, const float* __restrict__ embf,
                        float* __restrict__ h) {
    int idx = blockIdx.x * blockDim.x + threadIdx.x;  // N*D
    int i = idx >> 6, f = idx & 63;
    h[idx] = embf[x[i] * DD + f];
}

// ---------------- edge aggregation (segment_sum of h[src] into dst) ----------------
__global__ void k_aggr(const int* __restrict__ ei, const float* __restrict__ h,
                       float* __restrict__ aggr) {
    int idx = blockIdx.x * blockDim.x + threadIdx.x;  // E*D
    int e = idx >> 6, f = idx & 63;
    int s = ei[e];
    int d = ei[EE + e];
    atomicAdd(&aggr[d * DD + f], h[s * DD + f]);
}

// ---------------- SAGE layer: h' = LN(aggr/deg @ Wl + bl + h @ Wr) ----------------
// one wave (64 threads) per node; lane = output feature
__global__ void k_sage(const float* __restrict__ aggr, const int* __restrict__ degi,
                       const float* __restrict__ hin,
                       const float* __restrict__ Wl, const float* __restrict__ bl,
                       const float* __restrict__ Wr,
                       float* __restrict__ hout, float* __restrict__ hT) {
    int i = blockIdx.x;
    int f = threadIdx.x;
    __shared__ float sa[DD], sh[DD];
    float dg = (float)max(degi[i], 1);
    sa[f] = aggr[i * DD + f] / dg;
    sh[f] = hin[i * DD + f];
    __syncthreads();
    float o = bl[f];
    for (int k = 0; k < DD; ++k) {
        o += sa[k] * Wl[k * DD + f] + sh[k] * Wr[k * DD + f];
    }
    // LayerNorm across the 64 lanes (one wave)
    float m = o;
    for (int off = 32; off; off >>= 1) m += __shfl_xor(m, off);
    m *= (1.0f / DD);
    float d0 = o - m;
    float v = d0 * d0;
    for (int off = 32; off; off >>= 1) v += __shfl_xor(v, off);
    v *= (1.0f / DD);
    float r = d0 * rsqrtf(v + EPSF);
    hout[i * DD + f] = r;
    // transposed float4-chunk layout: hT4[(f>>2)*N + i] component (f&3)
    hT[(f >> 2) * (NN * 4) + i * 4 + (f & 3)] = r;
}

// ---------------- B-stage: vec_p / vec_q over all N^2 pairs ----------------
__launch_bounds__(256)
__global__ void k_bstage(const float* __restrict__ h, const float4* __restrict__ hT4,
                         const float* __restrict__ Wf, const unsigned int* __restrict__ eim,
                         float* __restrict__ vec_p, float* __restrict__ vec_q) {
    int bid = blockIdx.x;
    int dir = bid >> 10;          // 0 -> vec_p, 1 -> vec_q
    int fix = bid & 1023;
    const float* __restrict__ hrow = h + fix * DD;  // wave-uniform

    float vp[DD];
#pragma unroll
    for (int m = 0; m < DD; ++m) vp[m] = 0.f;

    for (int batch = 0; batch < NN; batch += 256) {
        int oth = batch + threadIdx.x;
        unsigned int pidx = (dir == 0) ? (unsigned int)(fix * NN + oth)
                                       : (unsigned int)(oth * NN + fix);
        float e = ((eim[pidx >> 5] >> (pidx & 31)) & 1u) ? 1.f : 0.f;

        float t[DD];
        {
            const float4* hb4 = (const float4*)(Wf + 65 * DD);
            const float4* w644 = (const float4*)(Wf + 64 * DD);
#pragma unroll
            for (int mq = 0; mq < 16; ++mq) {
                float4 hb = hb4[mq];
                float4 w6 = w644[mq];
                t[4 * mq + 0] = hb.x + e * w6.x;
                t[4 * mq + 1] = hb.y + e * w6.y;
                t[4 * mq + 2] = hb.z + e * w6.z;
                t[4 * mq + 3] = hb.w + e * w6.w;
            }
        }
        for (int kc = 0; kc < 16; ++kc) {
            float4 hv = hT4[kc * NN + oth];                         // per-lane, coalesced
            float4 hr = *(const float4*)(hrow + 4 * kc);            // uniform
            float q0 = hr.x * hv.x, q1 = hr.y * hv.y;
            float q2 = hr.z * hv.z, q3 = hr.w * hv.w;
            const float4* w0 = (const float4*)(Wf + (4 * kc + 0) * DD);
            const float4* w1 = (const float4*)(Wf + (4 * kc + 1) * DD);
            const float4* w2 = (const float4*)(Wf + (4 * kc + 2) * DD);
            const float4* w3 = (const float4*)(Wf + (4 * kc + 3) * DD);
#pragma unroll
            for (int mq = 0; mq < 16; ++mq) {
                float4 a0 = w0[mq], a1 = w1[mq], a2 = w2[mq], a3 = w3[mq];
                t[4 * mq + 0] += q0 * a0.x + q1 * a1.x + q2 * a2.x + q3 * a3.x;
                t[4 * mq + 1] += q0 * a0.y + q1 * a1.y + q2 * a2.y + q3 * a3.y;
                t[4 * mq + 2] += q0 * a0.z + q1 * a1.z + q2 * a2.z + q3 * a3.z;
                t[4 * mq + 3] += q0 * a0.w + q1 * a1.w + q2 * a2.w + q3 * a3.w;
            }
        }
        float mean = 0.f;
#pragma unroll
        for (int m = 0; m < DD; ++m) mean += t[m];
        mean *= (1.f / DD);
        float var = 0.f;
#pragma unroll
        for (int m = 0; m < DD; ++m) { float d0 = t[m] - mean; var += d0 * d0; }
        var *= (1.f / DD);
        float rs = rsqrtf(var + EPSF);
#pragma unroll
        for (int m = 0; m < DD; ++m) {
            float bm = (t[m] - mean) * rs;
            vp[m] += fmaxf(bm, 0.f);
        }
    }

    __shared__ float svec[DD];
    if (threadIdx.x < DD) svec[threadIdx.x] = 0.f;
    __syncthreads();
    int lane = threadIdx.x & 63;
#pragma unroll
    for (int m = 0; m < DD; ++m) {
        atomicAdd(&svec[(m + lane) & 63], vp[(m + lane) & 63]);
    }
    __syncthreads();
    if (threadIdx.x < DD) {
        float* dst = (dir == 0) ? vec_p : vec_q;
        dst[fix * DD + threadIdx.x] = svec[threadIdx.x];
    }
}

// ---------------- per-node projections ----------------
__global__ void k_ppqq(const float* __restrict__ vec, const float* __restrict__ gWf,
                       int row0, float* __restrict__ out) {
    int i = blockIdx.x;
    int f = threadIdx.x;
    __shared__ float sv[DD];
    sv[f] = vec[i * DD + f];
    __syncthreads();
    float o = 0.f;
    for (int k = 0; k < DD; ++k) o += sv[k] * gWf[(row0 + k) * DD + f];
    out[i * DD + f] = o;
}

// ---------------- final: G[a,b] * G[b,a] at selected pairs, dot with lin_W ----------------
__global__ void k_final(const int* __restrict__ pos, const float* __restrict__ h,
                        const float* __restrict__ gWf, const unsigned int* __restrict__ eim,
                        const float* __restrict__ pp, const float* __restrict__ qq,
                        const float* __restrict__ linf, const int* __restrict__ flag,
                        void* __restrict__ outv) {
    int p = blockIdx.x;
    int a = pos[2 * p], b = pos[2 * p + 1];
    int m = threadIdx.x;
    __shared__ float sq[DD];
    sq[m] = h[a * DD + m] * h[b * DD + m];
    __syncthreads();
    float acc = 0.f;
    for (int k = 0; k < DD; ++k) acc += sq[k] * gWf[k * DD + m];
    unsigned int iab = (unsigned int)(a * NN + b), iba = (unsigned int)(b * NN + a);
    float eab = ((eim[iab >> 5] >> (iab & 31)) & 1u) ? 1.f : 0.f;
    float eba = ((eim[iba >> 5] >> (iba & 31)) & 1u) ? 1.f : 0.f;
    float gb = gWf[193 * DD + m];
    float w64 = gWf[64 * DD + m];
    float u1 = acc + eab * w64 + pp[a * DD + m] + qq[b * DD + m] + gb;
    float u2 = acc + eba * w64 + pp[b * DD + m] + qq[a * DD + m] + gb;

    float m1 = u1;
    for (int off = 32; off; off >>= 1) m1 += __shfl_xor(m1, off);
    m1 *= (1.f / DD);
    float d1 = u1 - m1;
    float v1 = d1 * d1;
    for (int off = 32; off; off >>= 1) v1 += __shfl_xor(v1, off);
    v1 *= (1.f / DD);
    float g1 = fmaxf(d1 * rsqrtf(v1 + EPSF), 0.f);

    float m2 = u2;
    for (int off = 32; off; off >>= 1) m2 += __shfl_xor(m2, off);
    m2 *= (1.f / DD);
    float d2 = u2 - m2;
    float v2 = d2 * d2;
    for (int off = 32; off; off >>= 1) v2 += __shfl_xor(v2, off);
    v2 *= (1.f / DD);
    float g2 = fmaxf(d2 * rsqrtf(v2 + EPSF), 0.f);

    float r = g1 * g2 * linf[m];
    for (int off = 32; off; off >>= 1) r += __shfl_xor(r, off);
    if (m == 0) {
        float res = r + linf[DD];
        if (*flag) ((float*)outv)[p] = res;
        else       ((bf16*)outv)[p] = __float2bfloat16(res);
    }
}

extern "C" void kernel_launch(void* const* d_in, const int* in_sizes, int n_in,
                              void* d_out, int out_size, void* d_ws, size_t ws_size,
                              hipStream_t stream) {
    const int* x      = (const int*)d_in[0];
    const int* ei     = (const int*)d_in[1];
    const int* pos    = (const int*)d_in[2];
    const void* emb     = d_in[3];
    const void* sage_Wl = d_in[4];
    const void* sage_bl = d_in[5];
    const void* sage_Wr = d_in[6];
    const void* h_W     = d_in[7];
    const void* h_b     = d_in[8];
    const void* g_W     = d_in[9];
    const void* g_b     = d_in[10];
    const void* lin_W   = d_in[11];
    const void* lin_b   = d_in[12];

    char* w = (char*)d_ws;
    auto alloc = [&](size_t bytes) {
        void* p = (void*)w;
        w += (bytes + 255) & ~(size_t)255;
        return p;
    };
    float* hA   = (float*)alloc(NN * DD * 4);
    float* hB   = (float*)alloc(NN * DD * 4);
    float* hT4  = (float*)alloc(NN * DD * 4);
    float* aggr = (float*)alloc(NN * DD * 4);
    int*   degi = (int*)alloc(NN * 4);
    unsigned int* eim = (unsigned int*)alloc(NN * NN / 8);
    float* embf = (float*)alloc(101 * DD * 4);
    float* Wlf  = (float*)alloc(2 * DD * DD * 4);
    float* blf  = (float*)alloc(2 * DD * 4);
    float* Wrf  = (float*)alloc(2 * DD * DD * 4);
    float* Wf   = (float*)alloc(66 * DD * 4);    // h_W rows 0..64, h_b row 65
    float* gWf  = (float*)alloc(194 * DD * 4);   // g_W rows 0..192, g_b row 193
    float* linf = (float*)alloc(65 * 4);         // lin_W 0..63, lin_b 64
    float* vecp = (float*)alloc(NN * DD * 4);
    float* vecq = (float*)alloc(NN * DD * 4);
    float* ppb  = (float*)alloc(NN * DD * 4);
    float* qqb  = (float*)alloc(NN * DD * 4);
    int*   flag = (int*)alloc(256);

    hipMemsetAsync(flag, 0, 4, stream);
    hipMemsetAsync(degi, 0, NN * 4, stream);
    hipMemsetAsync(eim, 0, NN * NN / 8, stream);

    // dtype probe on emb (101*64 = 6464 halfwords is in-bounds for both dtypes)
    k_probe<<<(101 * DD + 255) / 256, 256, 0, stream>>>((const unsigned short*)emb, 101 * DD, flag);

    // decode all float inputs to fp32 workspace
    auto dec = [&](const void* src, float* dst, int n) {
        k_decode<<<(n + 255) / 256, 256, 0, stream>>>(src, dst, n, flag);
    };
    dec(emb, embf, 101 * DD);
    dec(sage_Wl, Wlf, 2 * DD * DD);
    dec(sage_bl, blf, 2 * DD);
    dec(sage_Wr, Wrf, 2 * DD * DD);
    dec(h_W, Wf, 65 * DD);
    dec(h_b, Wf + 65 * DD, DD);
    dec(g_W, gWf, 193 * DD);
    dec(g_b, gWf + 193 * DD, DD);
    dec(lin_W, linf, DD);
    dec(lin_b, linf + DD, 1);

    k_deg_eim<<<EE / 256, 256, 0, stream>>>(ei, degi, eim);
    k_embed<<<NN * DD / 256, 256, 0, stream>>>(x, embf, hA);

    // SAGE round 0: hA -> hB
    hipMemsetAsync(aggr, 0, NN * DD * 4, stream);
    k_aggr<<<EE * DD / 256, 256, 0, stream>>>(ei, hA, aggr);
    k_sage<<<NN, DD, 0, stream>>>(aggr, degi, hA, Wlf, blf, Wrf, hB, hT4);

    // SAGE round 1: hB -> hA (final h), also writes hT4
    hipMemsetAsync(aggr, 0, NN * DD * 4, stream);
    k_aggr<<<EE * DD / 256, 256, 0, stream>>>(ei, hB, aggr);
    k_sage<<<NN, DD, 0, stream>>>(aggr, degi, hB, Wlf + DD * DD, blf + DD,
                                  Wrf + DD * DD, hA, hT4);

    // B-stage: vec_p and vec_q
    k_bstage<<<2048, 256, 0, stream>>>(hA, (const float4*)hT4, Wf, eim, vecp, vecq);

    // per-node projections
    k_ppqq<<<NN, DD, 0, stream>>>(vecp, gWf, 65, ppb);
    k_ppqq<<<NN, DD, 0, stream>>>(vecq, gWf, 129, qqb);

    // final selected pairs
    k_final<<<PP, DD, 0, stream>>>(pos, hA, gWf, eim, ppb, qqb, linf, flag, d_out);
}

// Round 3
// 238.285 us; speedup vs baseline: 2.1459x; 2.1459x over previous
//
#include <hip/hip_runtime.h>
#include <hip/hip_bf16.h>

#define NN 1024
#define DD 64
#define EE 16384
#define PP 8192
#define EPSF 1e-5f

typedef __hip_bfloat16 bf16;
typedef __attribute__((ext_vector_type(8))) short short8;
typedef __attribute__((ext_vector_type(4))) float f32x4;

static __device__ __forceinline__ float b2f(bf16 v) { return __bfloat162float(v); }
static __device__ __forceinline__ short f2bf_s(float f) {
    bf16 h = __float2bfloat16(f);
    return *reinterpret_cast<short*>(&h);
}

// ---------------- dtype probe: detect fp32-vs-bf16 float inputs ----------------
__global__ void k_probe(const unsigned short* __restrict__ raw, int n, int* __restrict__ flag) {
    int i = blockIdx.x * blockDim.x + threadIdx.x;
    if (i >= n) return;
    unsigned int bits = ((unsigned int)raw[i]) << 16;
    float v = __uint_as_float(bits);
    if (!(fabsf(v) <= 1e3f)) atomicOr(flag, 1);
}

__global__ void k_decode(const void* __restrict__ src, float* __restrict__ dst, int n,
                         const int* __restrict__ flag) {
    int i = blockIdx.x * blockDim.x + threadIdx.x;
    if (i >= n) return;
    if (*flag) dst[i] = ((const float*)src)[i];
    else       dst[i] = b2f(((const bf16*)src)[i]);
}

// ---------------- degree + edge bitmaps (forward and transposed) ----------------
__global__ void k_deg_eim(const int* __restrict__ ei, int* __restrict__ deg,
                          unsigned int* __restrict__ eim, unsigned int* __restrict__ eimT) {
    int e = blockIdx.x * blockDim.x + threadIdx.x;
    if (e >= EE) return;
    int s = ei[e];
    int d = ei[EE + e];
    atomicAdd(&deg[d], 1);
    unsigned int idx = (unsigned int)(s * NN + d);
    atomicOr(&eim[idx >> 5], 1u << (idx & 31));
    unsigned int idxT = (unsigned int)(d * NN + s);
    atomicOr(&eimT[idxT >> 5], 1u << (idxT & 31));
}

// ---------------- embedding gather ----------------
__global__ void k_embed(const int* __restrict__ x, const float* __restrict__ embf,
                        float* __restrict__ h) {
    int idx = blockIdx.x * blockDim.x + threadIdx.x;  // N*D
    int i = idx >> 6, f = idx & 63;
    h[idx] = embf[x[i] * DD + f];
}

// ---------------- W transpose to bf16 for MFMA B-operand ----------------
// WbfT[n*64 + k] = bf16(h_W[k][n])
__global__ void k_wprep(const float* __restrict__ Wf, unsigned short* __restrict__ WbfT) {
    int idx = blockIdx.x * blockDim.x + threadIdx.x;  // 64*64
    int n = idx >> 6, k = idx & 63;
    bf16 h = __float2bfloat16(Wf[k * DD + n]);
    WbfT[n * DD + k] = *reinterpret_cast<unsigned short*>(&h);
}

// ---------------- edge aggregation ----------------
__global__ void k_aggr(const int* __restrict__ ei, const float* __restrict__ h,
                       float* __restrict__ aggr) {
    int idx = blockIdx.x * blockDim.x + threadIdx.x;  // E*D
    int e = idx >> 6, f = idx & 63;
    int s = ei[e];
    int d = ei[EE + e];
    atomicAdd(&aggr[d * DD + f], h[s * DD + f]);
}

// ---------------- SAGE layer ----------------
__global__ void k_sage(const float* __restrict__ aggr, const int* __restrict__ degi,
                       const float* __restrict__ hin,
                       const float* __restrict__ Wl, const float* __restrict__ bl,
                       const float* __restrict__ Wr,
                       float* __restrict__ hout) {
    int i = blockIdx.x;
    int f = threadIdx.x;
    __shared__ float sa[DD], sh[DD];
    float dg = (float)max(degi[i], 1);
    sa[f] = aggr[i * DD + f] / dg;
    sh[f] = hin[i * DD + f];
    __syncthreads();
    float o = bl[f];
    for (int k = 0; k < DD; ++k) {
        o += sa[k] * Wl[k * DD + f] + sh[k] * Wr[k * DD + f];
    }
    float m = o;
    for (int off = 32; off; off >>= 1) m += __shfl_xor(m, off);
    m *= (1.0f / DD);
    float d0 = o - m;
    float v = d0 * d0;
    for (int off = 32; off; off >>= 1) v += __shfl_xor(v, off);
    v *= (1.0f / DD);
    hout[i * DD + f] = d0 * rsqrtf(v + EPSF);
}

// ---------------- B-stage via MFMA ----------------
// blockIdx < 1024:  fix=i, rows=j, bits from eim  -> vec_p[i]
// blockIdx >= 1024: fix=j, rows=i, bits from eimT -> vec_q[j]
// Per 16-row group: T(16x64) = Q(16x64) @ h_W(64x64) via 8 mfma_16x16x32_bf16,
// where Q[r,k] = h_fix[k] * h_row[k]. Then + h_b + e*w64, LN over m, relu,
// column-sum accumulate.
__launch_bounds__(256)
__global__ void k_bstage(const float* __restrict__ h, const float* __restrict__ Wf,
                         const unsigned short* __restrict__ WbfT,
                         const unsigned int* __restrict__ eim,
                         const unsigned int* __restrict__ eimT,
                         float* __restrict__ vec_p, float* __restrict__ vec_q) {
    int bid = blockIdx.x;
    int dir = bid >> 10;
    int fix = bid & 1023;
    int tid = threadIdx.x;
    int lane = tid & 63;
    int wave = tid >> 6;
    int l15 = lane & 15;
    int quad = lane >> 4;  // 0..3

    const unsigned int* __restrict__ bm = dir ? eimT : eim;  // bit(fix*N + row)

    // B-operand frags: Wb[mt][kt] holds W[k = kt*32 + quad*8 + j][n = mt*16 + l15]
    short8 Wb[4][2];
#pragma unroll
    for (int mt = 0; mt < 4; ++mt)
#pragma unroll
        for (int kt = 0; kt < 2; ++kt) {
            int n = mt * 16 + l15;
            int k0 = kt * 32 + quad * 8;
            Wb[mt][kt] = *(const short8*)(WbfT + n * DD + k0);
        }

    // h_fix slice (fp32), per-lane k-range
    float hi[2][8];
#pragma unroll
    for (int kt = 0; kt < 2; ++kt) {
        const f32x4* p = (const f32x4*)(h + fix * DD + kt * 32 + quad * 8);
        f32x4 a = p[0], b = p[1];
#pragma unroll
        for (int j = 0; j < 4; ++j) { hi[kt][j] = a[j]; hi[kt][4 + j] = b[j]; }
    }

    // per-lane column constants
    float hbcol[4], w64col[4];
#pragma unroll
    for (int mt = 0; mt < 4; ++mt) {
        hbcol[mt]  = Wf[65 * DD + mt * 16 + l15];
        w64col[mt] = Wf[64 * DD + mt * 16 + l15];
    }

    float colacc[4] = {0.f, 0.f, 0.f, 0.f};

    for (int g = wave; g < 64; g += 4) {
        int jbase = g * 16;
        int jrow = jbase + l15;

        // A frags: Q[row = l15][k = kt*32 + quad*8 + j]
        short8 Aq[2];
#pragma unroll
        for (int kt = 0; kt < 2; ++kt) {
            const f32x4* p = (const f32x4*)(h + jrow * DD + kt * 32 + quad * 8);
            f32x4 a = p[0], b = p[1];
#pragma unroll
            for (int j = 0; j < 4; ++j) {
                Aq[kt][j]     = f2bf_s(hi[kt][j] * a[j]);
                Aq[kt][4 + j] = f2bf_s(hi[kt][4 + j] * b[j]);
            }
        }

        f32x4 C[4];
#pragma unroll
        for (int mt = 0; mt < 4; ++mt) C[mt] = (f32x4){0.f, 0.f, 0.f, 0.f};
#pragma unroll
        for (int kt = 0; kt < 2; ++kt)
#pragma unroll
            for (int mt = 0; mt < 4; ++mt)
                C[mt] = __builtin_amdgcn_mfma_f32_16x16x32_bf16(Aq[kt], Wb[mt][kt], C[mt], 0, 0, 0);

        // edge bits for the 16 rows of this group (uniform 32-bit word)
        unsigned int word = bm[(unsigned int)(fix * NN + jbase) >> 5];
        unsigned int slice = (word >> (jbase & 16)) & 0xFFFFu;
        float ef[4];
#pragma unroll
        for (int r = 0; r < 4; ++r) ef[r] = (float)((slice >> (quad * 4 + r)) & 1u);

        // + h_b + e*w64
#pragma unroll
        for (int mt = 0; mt < 4; ++mt)
#pragma unroll
            for (int r = 0; r < 4; ++r)
                C[mt][r] += hbcol[mt] + ef[r] * w64col[mt];

        // LN stats over m (columns): per-lane partials, then xor-reduce over 16-lane group
        float s[4], s2[4];
#pragma unroll
        for (int r = 0; r < 4; ++r) {
            s[r]  = C[0][r] + C[1][r] + C[2][r] + C[3][r];
            s2[r] = C[0][r] * C[0][r] + C[1][r] * C[1][r] + C[2][r] * C[2][r] + C[3][r] * C[3][r];
        }
#pragma unroll
        for (int step = 1; step < 16; step <<= 1) {
#pragma unroll
            for (int r = 0; r < 4; ++r) {
                s[r]  += __shfl_xor(s[r], step);
                s2[r] += __shfl_xor(s2[r], step);
            }
        }
        float mean[4], rs[4];
#pragma unroll
        for (int r = 0; r < 4; ++r) {
            mean[r] = s[r] * (1.f / DD);
            float var = fmaxf(s2[r] * (1.f / DD) - mean[r] * mean[r], 0.f);
            rs[r] = rsqrtf(var + EPSF);
        }
        // normalize, relu, column accumulate
#pragma unroll
        for (int mt = 0; mt < 4; ++mt)
#pragma unroll
            for (int r = 0; r < 4; ++r)
                colacc[mt] += fmaxf((C[mt][r] - mean[r]) * rs[r], 0.f);
    }

    // combine the 4 row-quads within the wave
#pragma unroll
    for (int step = 16; step < 64; step <<= 1)
#pragma unroll
        for (int mt = 0; mt < 4; ++mt) colacc[mt] += __shfl_xor(colacc[mt], step);

    __shared__ float red[4][DD];
    if (quad == 0) {
#pragma unroll
        for (int mt = 0; mt < 4; ++mt) red[wave][mt * 16 + l15] = colacc[mt];
    }
    __syncthreads();
    if (tid < DD) {
        float sum = red[0][tid] + red[1][tid] + red[2][tid] + red[3][tid];
        float* dst = dir ? vec_q : vec_p;
        dst[fix * DD + tid] = sum;
    }
}

// ---------------- per-node projections ----------------
__global__ void k_ppqq(const float* __restrict__ vec, const float* __restrict__ gWf,
                       int row0, float* __restrict__ out) {
    int i = blockIdx.x;
    int f = threadIdx.x;
    __shared__ float sv[DD];
    sv[f] = vec[i * DD + f];
    __syncthreads();
    float o = 0.f;
    for (int k = 0; k < DD; ++k) o += sv[k] * gWf[(row0 + k) * DD + f];
    out[i * DD + f] = o;
}

// ---------------- final: G[a,b]*G[b,a] at selected pairs ----------------
__global__ void k_final(const int* __restrict__ pos, const float* __restrict__ h,
                        const float* __restrict__ gWf, const unsigned int* __restrict__ eim,
                        const float* __restrict__ pp, const float* __restrict__ qq,
                        const float* __restrict__ linf, const int* __restrict__ flag,
                        void* __restrict__ outv) {
    int p = blockIdx.x;
    int a = pos[2 * p], b = pos[2 * p + 1];
    int m = threadIdx.x;
    __shared__ float sq[DD];
    sq[m] = h[a * DD + m] * h[b * DD + m];
    __syncthreads();
    float acc = 0.f;
    for (int k = 0; k < DD; ++k) acc += sq[k] * gWf[k * DD + m];
    unsigned int iab = (unsigned int)(a * NN + b), iba = (unsigned int)(b * NN + a);
    float eab = ((eim[iab >> 5] >> (iab & 31)) & 1u) ? 1.f : 0.f;
    float eba = ((eim[iba >> 5] >> (iba & 31)) & 1u) ? 1.f : 0.f;
    float gb = gWf[193 * DD + m];
    float w64 = gWf[64 * DD + m];
    float u1 = acc + eab * w64 + pp[a * DD + m] + qq[b * DD + m] + gb;
    float u2 = acc + eba * w64 + pp[b * DD + m] + qq[a * DD + m] + gb;

    float m1 = u1;
    for (int off = 32; off; off >>= 1) m1 += __shfl_xor(m1, off);
    m1 *= (1.f / DD);
    float d1 = u1 - m1;
    float v1 = d1 * d1;
    for (int off = 32; off; off >>= 1) v1 += __shfl_xor(v1, off);
    v1 *= (1.f / DD);
    float g1 = fmaxf(d1 * rsqrtf(v1 + EPSF), 0.f);

    float m2 = u2;
    for (int off = 32; off; off >>= 1) m2 += __shfl_xor(m2, off);
    m2 *= (1.f / DD);
    float d2 = u2 - m2;
    float v2 = d2 * d2;
    for (int off = 32; off; off >>= 1) v2 += __shfl_xor(v2, off);
    v2 *= (1.f / DD);
    float g2 = fmaxf(d2 * rsqrtf(v2 + EPSF), 0.f);

    float r = g1 * g2 * linf[m];
    for (int off = 32; off; off >>= 1) r += __shfl_xor(r, off);
    if (m == 0) {
        float res = r + linf[DD];
        if (*flag) ((float*)outv)[p] = res;
        else       ((bf16*)outv)[p] = __float2bfloat16(res);
    }
}

extern "C" void kernel_launch(void* const* d_in, const int* in_sizes, int n_in,
                              void* d_out, int out_size, void* d_ws, size_t ws_size,
                              hipStream_t stream) {
    const int* x      = (const int*)d_in[0];
    const int* ei     = (const int*)d_in[1];
    const int* pos    = (const int*)d_in[2];
    const void* emb     = d_in[3];
    const void* sage_Wl = d_in[4];
    const void* sage_bl = d_in[5];
    const void* sage_Wr = d_in[6];
    const void* h_W     = d_in[7];
    const void* h_b     = d_in[8];
    const void* g_W     = d_in[9];
    const void* g_b     = d_in[10];
    const void* lin_W   = d_in[11];
    const void* lin_b   = d_in[12];

    char* w = (char*)d_ws;
    auto alloc = [&](size_t bytes) {
        void* p = (void*)w;
        w += (bytes + 255) & ~(size_t)255;
        return p;
    };
    float* hA   = (float*)alloc(NN * DD * 4);
    float* hB   = (float*)alloc(NN * DD * 4);
    float* aggr = (float*)alloc(NN * DD * 4);
    int*   degi = (int*)alloc(NN * 4);
    unsigned int* eim  = (unsigned int*)alloc(NN * NN / 8);
    unsigned int* eimT = (unsigned int*)alloc(NN * NN / 8);
    float* embf = (float*)alloc(101 * DD * 4);
    float* Wlf  = (float*)alloc(2 * DD * DD * 4);
    float* blf  = (float*)alloc(2 * DD * 4);
    float* Wrf  = (float*)alloc(2 * DD * DD * 4);
    float* Wf   = (float*)alloc(66 * DD * 4);    // h_W rows 0..64, h_b row 65
    unsigned short* WbfT = (unsigned short*)alloc(DD * DD * 2);
    float* gWf  = (float*)alloc(194 * DD * 4);   // g_W rows 0..192, g_b row 193
    float* linf = (float*)alloc(65 * 4);
    float* vecp = (float*)alloc(NN * DD * 4);
    float* vecq = (float*)alloc(NN * DD * 4);
    float* ppb  = (float*)alloc(NN * DD * 4);
    float* qqb  = (float*)alloc(NN * DD * 4);
    int*   flag = (int*)alloc(256);

    hipMemsetAsync(flag, 0, 4, stream);
    hipMemsetAsync(degi, 0, NN * 4, stream);
    hipMemsetAsync(eim, 0, NN * NN / 8, stream);
    hipMemsetAsync(eimT, 0, NN * NN / 8, stream);

    k_probe<<<(101 * DD + 255) / 256, 256, 0, stream>>>((const unsigned short*)emb, 101 * DD, flag);

    auto dec = [&](const void* src, float* dst, int n) {
        k_decode<<<(n + 255) / 256, 256, 0, stream>>>(src, dst, n, flag);
    };
    dec(emb, embf, 101 * DD);
    dec(sage_Wl, Wlf, 2 * DD * DD);
    dec(sage_bl, blf, 2 * DD);
    dec(sage_Wr, Wrf, 2 * DD * DD);
    dec(h_W, Wf, 65 * DD);
    dec(h_b, Wf + 65 * DD, DD);
    dec(g_W, gWf, 193 * DD);
    dec(g_b, gWf + 193 * DD, DD);
    dec(lin_W, linf, DD);
    dec(lin_b, linf + DD, 1);

    k_wprep<<<DD * DD / 256, 256, 0, stream>>>(Wf, WbfT);
    k_deg_eim<<<EE / 256, 256, 0, stream>>>(ei, degi, eim, eimT);
    k_embed<<<NN * DD / 256, 256, 0, stream>>>(x, embf, hA);

    // SAGE round 0: hA -> hB
    hipMemsetAsync(aggr, 0, NN * DD * 4, stream);
    k_aggr<<<EE * DD / 256, 256, 0, stream>>>(ei, hA, aggr);
    k_sage<<<NN, DD, 0, stream>>>(aggr, degi, hA, Wlf, blf, Wrf, hB);

    // SAGE round 1: hB -> hA (final h)
    hipMemsetAsync(aggr, 0, NN * DD * 4, stream);
    k_aggr<<<EE * DD / 256, 256, 0, stream>>>(ei, hB, aggr);
    k_sage<<<NN, DD, 0, stream>>>(aggr, degi, hB, Wlf + DD * DD, blf + DD,
                                  Wrf + DD * DD, hA);

    // B-stage (MFMA): vec_p and vec_q
    k_bstage<<<2048, 256, 0, stream>>>(hA, Wf, WbfT, eim, eimT, vecp, vecq);

    // per-node projections
    k_ppqq<<<NN, DD, 0, stream>>>(vecp, gWf, 65, ppb);
    k_ppqq<<<NN, DD, 0, stream>>>(vecq, gWf, 129, qqb);

    // final selected pairs
    k_final<<<PP, DD, 0, stream>>>(pos, hA, gWf, eim, ppb, qqb, linf, flag, d_out);
}

// Round 4
// 173.809 us; speedup vs baseline: 2.9420x; 1.3710x over previous
//
#include <hip/hip_runtime.h>
#include <hip/hip_bf16.h>

#define NN 1024
#define DD 64
#define EE 16384
#define PP 8192
#define EPSF 1e-5f

typedef __hip_bfloat16 bf16;
typedef __attribute__((ext_vector_type(8))) short short8;
typedef __attribute__((ext_vector_type(4))) float f32x4;

static __device__ __forceinline__ float dec1(const void* src, int i, int fl) {
    if (fl) return ((const float*)src)[i];
    return __bfloat162float(((const bf16*)src)[i]);
}
static __device__ __forceinline__ unsigned short f2bf_u(float f) {
    bf16 h = __float2bfloat16(f);
    return *reinterpret_cast<unsigned short*>(&h);
}

// ---------------- dtype probe ----------------
__global__ void k_probe(const unsigned short* __restrict__ raw, int n, int* __restrict__ flag) {
    int i = blockIdx.x * blockDim.x + threadIdx.x;
    if (i >= n) return;
    unsigned int bits = ((unsigned int)raw[i]) << 16;
    float v = __uint_as_float(bits);
    if (!(fabsf(v) <= 1e3f)) atomicOr(flag, 1);
}

// ---------------- fused prep: all decodes + transpose + embed + deg/eim ----------------
__global__ void k_prep(const void* __restrict__ emb, const void* __restrict__ sWl,
                       const void* __restrict__ sbl, const void* __restrict__ sWr,
                       const void* __restrict__ hW, const void* __restrict__ hb,
                       const void* __restrict__ gW, const void* __restrict__ gb,
                       const void* __restrict__ lW, const void* __restrict__ lb,
                       const int* __restrict__ x, const int* __restrict__ ei,
                       const int* __restrict__ flagp,
                       float* __restrict__ Wlf, float* __restrict__ blf, float* __restrict__ Wrf,
                       float* __restrict__ WfT, float* __restrict__ hbw,
                       float* __restrict__ gWf, float* __restrict__ linf,
                       float* __restrict__ h0, int* __restrict__ deg,
                       unsigned int* __restrict__ eim, unsigned int* __restrict__ eimT) {
    int fl = *flagp;
    int b = blockIdx.x, t = threadIdx.x;
    if (b < 32) {                                   // sage_Wl: 2*64*64
        int i = b * 256 + t; Wlf[i] = dec1(sWl, i, fl);
    } else if (b < 33) {                            // sage_bl: 128
        if (t < 128) blf[t] = dec1(sbl, t, fl);
    } else if (b < 65) {                            // sage_Wr
        int i = (b - 33) * 256 + t; Wrf[i] = dec1(sWr, i, fl);
    } else if (b < 82) {                            // h_W transpose + h_b/w64
        int i = (b - 65) * 256 + t;
        if (i < 4096) { int n = i >> 6, k = i & 63; WfT[n * DD + k] = dec1(hW, k * DD + n, fl); }
        else if (i < 4160) { hbw[i - 4096] = dec1(hb, i - 4096, fl); }            // h_b
        else if (i < 4224) { hbw[64 + (i - 4160)] = dec1(hW, 64 * DD + (i - 4160), fl); } // w64 row
    } else if (b < 131) {                           // g_W + g_b
        int i = (b - 82) * 256 + t;
        if (i < 193 * DD) gWf[i] = dec1(gW, i, fl);
        else if (i < 194 * DD) gWf[i] = dec1(gb, i - 193 * DD, fl);
    } else if (b < 132) {                           // lin
        if (t < DD) linf[t] = dec1(lW, t, fl);
        else if (t == DD) linf[DD] = dec1(lb, 0, fl);
    } else if (b < 388) {                           // embedding gather
        int i = (b - 132) * 256 + t;
        int node = i >> 6, f = i & 63;
        h0[i] = dec1(emb, x[node] * DD + f, fl);
    } else {                                        // degree + bitmaps
        int e = (b - 388) * 256 + t;
        if (e < EE) {
            int s = ei[e], d = ei[EE + e];
            atomicAdd(&deg[d], 1);
            unsigned int idx = (unsigned int)(s * NN + d);
            atomicOr(&eim[idx >> 5], 1u << (idx & 31));
            unsigned int idxT = (unsigned int)(d * NN + s);
            atomicOr(&eimT[idxT >> 5], 1u << (idxT & 31));
        }
    }
}

// ---------------- edge aggregation ----------------
__global__ void k_aggr(const int* __restrict__ ei, const float* __restrict__ h,
                       float* __restrict__ aggr) {
    int idx = blockIdx.x * blockDim.x + threadIdx.x;  // E*D
    int e = idx >> 6, f = idx & 63;
    int s = ei[e];
    int d = ei[EE + e];
    atomicAdd(&aggr[d * DD + f], h[s * DD + f]);
}

// ---------------- SAGE layer (+ optional aggr re-zero, + bf16 h output) ----------------
__global__ void k_sage(const float* __restrict__ aggr, const int* __restrict__ degi,
                       const float* __restrict__ hin,
                       const float* __restrict__ Wl, const float* __restrict__ bl,
                       const float* __restrict__ Wr,
                       float* __restrict__ hout, unsigned short* __restrict__ hbf,
                       float* __restrict__ azero) {
    int i = blockIdx.x;
    int f = threadIdx.x;
    __shared__ float sa[DD], sh[DD];
    float dg = (float)max(degi[i], 1);
    sa[f] = aggr[i * DD + f] / dg;
    sh[f] = hin[i * DD + f];
    if (azero) azero[i * DD + f] = 0.f;   // own slice; safe (zero for next round)
    __syncthreads();
    float o = bl[f];
    for (int k = 0; k < DD; ++k) {
        o += sa[k] * Wl[k * DD + f] + sh[k] * Wr[k * DD + f];
    }
    float m = o;
    for (int off = 32; off; off >>= 1) m += __shfl_xor(m, off);
    m *= (1.0f / DD);
    float d0 = o - m;
    float v = d0 * d0;
    for (int off = 32; off; off >>= 1) v += __shfl_xor(v, off);
    v *= (1.0f / DD);
    float r = d0 * rsqrtf(v + EPSF);
    hout[i * DD + f] = r;
    hbf[i * DD + f] = f2bf_u(r);
}

// ---------------- LN pass over a 16x64 tile in C-layout ----------------
static __device__ __forceinline__ void ln_pass(const f32x4* C, unsigned int slice, int quad,
                                               const float* hw0, const float* hw1,
                                               float* acc) {
    float T[4][4];
    float s[4], s2[4];
#pragma unroll
    for (int r = 0; r < 4; ++r) {
        bool e = (slice >> (quad * 4 + r)) & 1u;
        s[r] = 0.f; s2[r] = 0.f;
#pragma unroll
        for (int mt = 0; mt < 4; ++mt) {
            float v = C[mt][r] + (e ? hw1[mt] : hw0[mt]);
            T[mt][r] = v;
            s[r] += v;
            s2[r] += v * v;
        }
    }
#pragma unroll
    for (int step = 1; step < 16; step <<= 1) {
#pragma unroll
        for (int r = 0; r < 4; ++r) {
            s[r]  += __shfl_xor(s[r], step);
            s2[r] += __shfl_xor(s2[r], step);
        }
    }
#pragma unroll
    for (int r = 0; r < 4; ++r) {
        float mean = s[r] * (1.f / DD);
        float var = fmaxf(s2[r] * (1.f / DD) - mean * mean, 0.f);
        float rs = rsqrtf(var + EPSF);
#pragma unroll
        for (int mt = 0; mt < 4; ++mt)
            acc[mt] += fmaxf((T[mt][r] - mean) * rs, 0.f);
    }
}

// ---------------- merged B-stage: one block per node computes vec_p[fix] AND vec_q[fix] ----------------
// T = Q @ h_W with Q[j,k] = h_fix[k]*h_j[k]  ==  h_j @ (diag(h_fix) @ h_W).
// Scaled W built once per block in LDS (bf16); A-frags are pure loads of precomputed bf16 h.
// Forward (B[fix,j]) and backward (B[j,fix]) tiles share the MFMA result; only edge-bit bias
// differs. Fast path when the two bit-slices are equal.
__launch_bounds__(256)
__global__ void k_bstage(const float* __restrict__ h0, const unsigned short* __restrict__ hbf,
                         const float* __restrict__ WfT, const float* __restrict__ hbw,
                         const unsigned int* __restrict__ eim,
                         const unsigned int* __restrict__ eimT,
                         float* __restrict__ vec_p, float* __restrict__ vec_q) {
    int fix = blockIdx.x;
    int tid = threadIdx.x;
    int lane = tid & 63, wave = tid >> 6;
    int l15 = lane & 15, quad = lane >> 4;

    __shared__ unsigned short sW[DD * DD];   // [n][k], bf16 of h_fix[k] * h_W[k][n]
    __shared__ float red[4][2 * DD];

    {
        int n = tid >> 2;
        int k0 = (tid & 3) * 16;
        const float* hi = h0 + fix * DD;
#pragma unroll
        for (int u = 0; u < 16; ++u) {
            int k = k0 + u;
            sW[n * DD + k] = f2bf_u(hi[k] * WfT[n * DD + k]);
        }
    }
    __syncthreads();

    short8 Wb[4][2];
#pragma unroll
    for (int mt = 0; mt < 4; ++mt)
#pragma unroll
        for (int kt = 0; kt < 2; ++kt)
            Wb[mt][kt] = *(const short8*)(sW + (mt * 16 + l15) * DD + kt * 32 + quad * 8);

    float hw0[4], hw1[4];
#pragma unroll
    for (int mt = 0; mt < 4; ++mt) {
        float a = hbw[mt * 16 + l15];
        float w = hbw[64 + mt * 16 + l15];
        hw0[mt] = a;
        hw1[mt] = a + w;
    }

    float accf[4] = {0.f, 0.f, 0.f, 0.f};
    float accb[4] = {0.f, 0.f, 0.f, 0.f};

    for (int g = wave; g < 64; g += 4) {
        int jrow = g * 16 + l15;
        short8 A0 = *(const short8*)(hbf + jrow * DD + quad * 8);
        short8 A1 = *(const short8*)(hbf + jrow * DD + 32 + quad * 8);

        f32x4 C[4];
#pragma unroll
        for (int mt = 0; mt < 4; ++mt) C[mt] = (f32x4){0.f, 0.f, 0.f, 0.f};
#pragma unroll
        for (int mt = 0; mt < 4; ++mt)
            C[mt] = __builtin_amdgcn_mfma_f32_16x16x32_bf16(A0, Wb[mt][0], C[mt], 0, 0, 0);
#pragma unroll
        for (int mt = 0; mt < 4; ++mt)
            C[mt] = __builtin_amdgcn_mfma_f32_16x16x32_bf16(A1, Wb[mt][1], C[mt], 0, 0, 0);

        unsigned int base = (unsigned int)(fix * NN + g * 16);
        unsigned int sf = (eim[base >> 5]  >> (base & 31)) & 0xFFFFu;
        unsigned int sb = (eimT[base >> 5] >> (base & 31)) & 0xFFFFu;

        if (sf == sb) {
            float tot[4] = {0.f, 0.f, 0.f, 0.f};
            ln_pass(C, sf, quad, hw0, hw1, tot);
#pragma unroll
            for (int mt = 0; mt < 4; ++mt) { accf[mt] += tot[mt]; accb[mt] += tot[mt]; }
        } else {
            ln_pass(C, sf, quad, hw0, hw1, accf);
            ln_pass(C, sb, quad, hw0, hw1, accb);
        }
    }

#pragma unroll
    for (int step = 16; step < 64; step <<= 1)
#pragma unroll
        for (int mt = 0; mt < 4; ++mt) {
            accf[mt] += __shfl_xor(accf[mt], step);
            accb[mt] += __shfl_xor(accb[mt], step);
        }

    if (quad == 0) {
#pragma unroll
        for (int mt = 0; mt < 4; ++mt) {
            red[wave][mt * 16 + l15] = accf[mt];
            red[wave][DD + mt * 16 + l15] = accb[mt];
        }
    }
    __syncthreads();
    if (tid < 2 * DD) {
        float sum = red[0][tid] + red[1][tid] + red[2][tid] + red[3][tid];
        if (tid < DD) vec_p[fix * DD + tid] = sum;
        else          vec_q[fix * DD + (tid - DD)] = sum;
    }
}

// ---------------- fused per-node projections ----------------
__global__ void k_ppqq2(const float* __restrict__ vecp, const float* __restrict__ vecq,
                        const float* __restrict__ gWf,
                        float* __restrict__ ppb, float* __restrict__ qqb) {
    int b = blockIdx.x;
    int f = threadIdx.x;
    int i = b & 1023, which = b >> 10;
    const float* vec = (which ? vecq : vecp) + i * DD;
    int row0 = which ? 129 : 65;
    __shared__ float sv[DD];
    sv[f] = vec[f];
    __syncthreads();
    float o = 0.f;
    for (int k = 0; k < DD; ++k) o += sv[k] * gWf[(row0 + k) * DD + f];
    (which ? qqb : ppb)[i * DD + f] = o;
}

// ---------------- final: G[a,b]*G[b,a] at selected pairs ----------------
__global__ void k_final(const int* __restrict__ pos, const float* __restrict__ h,
                        const float* __restrict__ gWf, const unsigned int* __restrict__ eim,
                        const float* __restrict__ pp, const float* __restrict__ qq,
                        const float* __restrict__ linf, const int* __restrict__ flag,
                        void* __restrict__ outv) {
    int p = blockIdx.x;
    int a = pos[2 * p], b = pos[2 * p + 1];
    int m = threadIdx.x;
    __shared__ float sq[DD];
    sq[m] = h[a * DD + m] * h[b * DD + m];
    __syncthreads();
    float acc = 0.f;
    for (int k = 0; k < DD; ++k) acc += sq[k] * gWf[k * DD + m];
    unsigned int iab = (unsigned int)(a * NN + b), iba = (unsigned int)(b * NN + a);
    float eab = ((eim[iab >> 5] >> (iab & 31)) & 1u) ? 1.f : 0.f;
    float eba = ((eim[iba >> 5] >> (iba & 31)) & 1u) ? 1.f : 0.f;
    float gb = gWf[193 * DD + m];
    float w64 = gWf[64 * DD + m];
    float u1 = acc + eab * w64 + pp[a * DD + m] + qq[b * DD + m] + gb;
    float u2 = acc + eba * w64 + pp[b * DD + m] + qq[a * DD + m] + gb;

    float m1 = u1;
    for (int off = 32; off; off >>= 1) m1 += __shfl_xor(m1, off);
    m1 *= (1.f / DD);
    float d1 = u1 - m1;
    float v1 = d1 * d1;
    for (int off = 32; off; off >>= 1) v1 += __shfl_xor(v1, off);
    v1 *= (1.f / DD);
    float g1 = fmaxf(d1 * rsqrtf(v1 + EPSF), 0.f);

    float m2 = u2;
    for (int off = 32; off; off >>= 1) m2 += __shfl_xor(m2, off);
    m2 *= (1.f / DD);
    float d2 = u2 - m2;
    float v2 = d2 * d2;
    for (int off = 32; off; off >>= 1) v2 += __shfl_xor(v2, off);
    v2 *= (1.f / DD);
    float g2 = fmaxf(d2 * rsqrtf(v2 + EPSF), 0.f);

    float r = g1 * g2 * linf[m];
    for (int off = 32; off; off >>= 1) r += __shfl_xor(r, off);
    if (m == 0) {
        float res = r + linf[DD];
        if (*flag) ((float*)outv)[p] = res;
        else       ((bf16*)outv)[p] = __float2bfloat16(res);
    }
}

extern "C" void kernel_launch(void* const* d_in, const int* in_sizes, int n_in,
                              void* d_out, int out_size, void* d_ws, size_t ws_size,
                              hipStream_t stream) {
    const int* x      = (const int*)d_in[0];
    const int* ei     = (const int*)d_in[1];
    const int* pos    = (const int*)d_in[2];
    const void* emb     = d_in[3];
    const void* sage_Wl = d_in[4];
    const void* sage_bl = d_in[5];
    const void* sage_Wr = d_in[6];
    const void* h_W     = d_in[7];
    const void* h_b     = d_in[8];
    const void* g_W     = d_in[9];
    const void* g_b     = d_in[10];
    const void* lin_W   = d_in[11];
    const void* lin_b   = d_in[12];

    char* w = (char*)d_ws;
    auto alloc = [&](size_t bytes) {
        void* p = (void*)w;
        w += (bytes + 255) & ~(size_t)255;
        return p;
    };
    // ---- contiguous zero region (single memset) ----
    int*   flag = (int*)alloc(256);
    int*   degi = (int*)alloc(NN * 4);
    unsigned int* eim  = (unsigned int*)alloc(NN * NN / 8);
    unsigned int* eimT = (unsigned int*)alloc(NN * NN / 8);
    float* aggr = (float*)alloc(NN * DD * 4);
    size_t zero_bytes = (size_t)((char*)w - (char*)d_ws);
    // ---- rest ----
    float* h0   = (float*)alloc(NN * DD * 4);
    float* h1   = (float*)alloc(NN * DD * 4);
    float* h2   = (float*)alloc(NN * DD * 4);
    unsigned short* hbf = (unsigned short*)alloc(NN * DD * 2);
    float* Wlf  = (float*)alloc(2 * DD * DD * 4);
    float* blf  = (float*)alloc(2 * DD * 4);
    float* Wrf  = (float*)alloc(2 * DD * DD * 4);
    float* WfT  = (float*)alloc(DD * DD * 4);     // h_W[0:64] transposed [n][k]
    float* hbw  = (float*)alloc(128 * 4);          // [0:64]=h_b, [64:128]=w64 row
    float* gWf  = (float*)alloc(194 * DD * 4);
    float* linf = (float*)alloc(65 * 4);
    float* vecp = (float*)alloc(NN * DD * 4);
    float* vecq = (float*)alloc(NN * DD * 4);
    float* ppb  = (float*)alloc(NN * DD * 4);
    float* qqb  = (float*)alloc(NN * DD * 4);

    hipMemsetAsync(d_ws, 0, zero_bytes, stream);

    k_probe<<<(101 * DD + 255) / 256, 256, 0, stream>>>((const unsigned short*)emb, 101 * DD, flag);

    k_prep<<<452, 256, 0, stream>>>(emb, sage_Wl, sage_bl, sage_Wr, h_W, h_b, g_W, g_b,
                                    lin_W, lin_b, x, ei, flag,
                                    Wlf, blf, Wrf, WfT, hbw, gWf, linf,
                                    h0, degi, eim, eimT);

    // SAGE round 0: h0 -> h1 (zeroes aggr for round 1)
    k_aggr<<<EE * DD / 256, 256, 0, stream>>>(ei, h0, aggr);
    k_sage<<<NN, DD, 0, stream>>>(aggr, degi, h0, Wlf, blf, Wrf, h1, hbf, aggr);

    // SAGE round 1: h1 -> h2 (final), writes hbf
    k_aggr<<<EE * DD / 256, 256, 0, stream>>>(ei, h1, aggr);
    k_sage<<<NN, DD, 0, stream>>>(aggr, degi, h1, Wlf + DD * DD, blf + DD,
                                  Wrf + DD * DD, h2, hbf, (float*)nullptr);

    // merged B-stage
    k_bstage<<<NN, 256, 0, stream>>>(h0 /*unused-safe*/ == h0 ? h2 : h2, hbf, WfT, hbw, eim, eimT, vecp, vecq);

    // per-node projections (both in one launch)
    k_ppqq2<<<2 * NN, DD, 0, stream>>>(vecp, vecq, gWf, ppb, qqb);

    // final selected pairs
    k_final<<<PP, DD, 0, stream>>>(pos, h2, gWf, eim, ppb, qqb, linf, flag, d_out);
}

// Round 5
// 167.902 us; speedup vs baseline: 3.0455x; 1.0352x over previous
//
#include <hip/hip_runtime.h>
#include <hip/hip_bf16.h>

#define NN 1024
#define DD 64
#define EE 16384
#define PP 8192
#define EPSF 1e-5f
#define SWP (DD + 8)   // padded LDS row stride (shorts): 144 B, 16B-aligned, conflict-free

typedef __hip_bfloat16 bf16;
typedef __attribute__((ext_vector_type(8))) short short8;
typedef __attribute__((ext_vector_type(4))) float f32x4;

static __device__ __forceinline__ float dec1(const void* src, int i, int fl) {
    if (fl) return ((const float*)src)[i];
    return __bfloat162float(((const bf16*)src)[i]);
}
static __device__ __forceinline__ unsigned short f2bf_u(float f) {
    bf16 h = __float2bfloat16(f);
    return *reinterpret_cast<unsigned short*>(&h);
}
static __device__ __forceinline__ float bfu2f(unsigned short u) {
    unsigned int b = ((unsigned int)u) << 16;
    return __uint_as_float(b);
}

// ---------------- dtype probe ----------------
__global__ void k_probe(const unsigned short* __restrict__ raw, int n, int* __restrict__ flag) {
    int i = blockIdx.x * blockDim.x + threadIdx.x;
    if (i >= n) return;
    unsigned int bits = ((unsigned int)raw[i]) << 16;
    float v = __uint_as_float(bits);
    if (!(fabsf(v) <= 1e3f)) atomicOr(flag, 1);
}

// ---------------- fused prep ----------------
__global__ void k_prep(const void* __restrict__ emb, const void* __restrict__ sWl,
                       const void* __restrict__ sbl, const void* __restrict__ sWr,
                       const void* __restrict__ hW, const void* __restrict__ hb,
                       const void* __restrict__ gW, const void* __restrict__ gb,
                       const void* __restrict__ lW, const void* __restrict__ lb,
                       const int* __restrict__ x, const int* __restrict__ ei,
                       const int* __restrict__ flagp,
                       float* __restrict__ Wlf, float* __restrict__ blf, float* __restrict__ Wrf,
                       float* __restrict__ WfT, float* __restrict__ hbw,
                       float* __restrict__ gWf, float* __restrict__ linf,
                       float* __restrict__ h0, int* __restrict__ deg,
                       unsigned int* __restrict__ eim, unsigned int* __restrict__ eimT) {
    int fl = *flagp;
    int b = blockIdx.x, t = threadIdx.x;
    if (b < 32) {
        int i = b * 256 + t; Wlf[i] = dec1(sWl, i, fl);
    } else if (b < 33) {
        if (t < 128) blf[t] = dec1(sbl, t, fl);
    } else if (b < 65) {
        int i = (b - 33) * 256 + t; Wrf[i] = dec1(sWr, i, fl);
    } else if (b < 82) {
        int i = (b - 65) * 256 + t;
        if (i < 4096) { int n = i >> 6, k = i & 63; WfT[n * DD + k] = dec1(hW, k * DD + n, fl); }
        else if (i < 4160) { hbw[i - 4096] = dec1(hb, i - 4096, fl); }
        else if (i < 4224) { hbw[64 + (i - 4160)] = dec1(hW, 64 * DD + (i - 4160), fl); }
    } else if (b < 131) {
        int i = (b - 82) * 256 + t;
        if (i < 193 * DD) gWf[i] = dec1(gW, i, fl);
        else if (i < 194 * DD) gWf[i] = dec1(gb, i - 193 * DD, fl);
    } else if (b < 132) {
        if (t < DD) linf[t] = dec1(lW, t, fl);
        else if (t == DD) linf[DD] = dec1(lb, 0, fl);
    } else if (b < 388) {
        int i = (b - 132) * 256 + t;
        int node = i >> 6, f = i & 63;
        h0[i] = dec1(emb, x[node] * DD + f, fl);
    } else {
        int e = (b - 388) * 256 + t;
        if (e < EE) {
            int s = ei[e], d = ei[EE + e];
            atomicAdd(&deg[d], 1);
            unsigned int idx = (unsigned int)(s * NN + d);
            atomicOr(&eim[idx >> 5], 1u << (idx & 31));
            unsigned int idxT = (unsigned int)(d * NN + s);
            atomicOr(&eimT[idxT >> 5], 1u << (idxT & 31));
        }
    }
}

// ---------------- prefix scan: deg -> rowptr (exclusive), cursor copy ----------------
__global__ void k_scan(const int* __restrict__ deg, int* __restrict__ rowptr,
                       int* __restrict__ cursor) {
    __shared__ int tmp[NN];
    int t = threadIdx.x;
    int v = deg[t];
    tmp[t] = v;
    __syncthreads();
    for (int off = 1; off < NN; off <<= 1) {
        int add = (t >= off) ? tmp[t - off] : 0;
        __syncthreads();
        tmp[t] += add;
        __syncthreads();
    }
    int incl = tmp[t];
    rowptr[t] = incl - v;
    cursor[t] = incl - v;
    if (t == NN - 1) rowptr[NN] = incl;
}

// ---------------- scatter edges into CSR by dst ----------------
__global__ void k_scatter(const int* __restrict__ ei, int* __restrict__ cursor,
                          int* __restrict__ csrc) {
    int e = blockIdx.x * blockDim.x + threadIdx.x;
    if (e >= EE) return;
    int d = ei[EE + e];
    int c = atomicAdd(&cursor[d], 1);
    csrc[c] = ei[e];
}

// ---------------- SAGE layer with fused CSR aggregation ----------------
__global__ void k_sage(const int* __restrict__ rowptr, const int* __restrict__ csrc,
                       const float* __restrict__ hin,
                       const float* __restrict__ Wl, const float* __restrict__ bl,
                       const float* __restrict__ Wr,
                       float* __restrict__ hout, unsigned short* __restrict__ hbf) {
    int i = blockIdx.x;
    int f = threadIdx.x;
    __shared__ float sa[DD], sh[DD];
    int r0 = rowptr[i], r1 = rowptr[i + 1];
    float s = 0.f;
    for (int r = r0; r < r1; ++r) {
        int src = csrc[r];
        s += hin[src * DD + f];
    }
    float dg = (float)max(r1 - r0, 1);
    sa[f] = s / dg;
    sh[f] = hin[i * DD + f];
    __syncthreads();
    float o = bl[f];
    for (int k = 0; k < DD; ++k) {
        o += sa[k] * Wl[k * DD + f] + sh[k] * Wr[k * DD + f];
    }
    float m = o;
    for (int off = 32; off; off >>= 1) m += __shfl_xor(m, off);
    m *= (1.0f / DD);
    float d0 = o - m;
    float v = d0 * d0;
    for (int off = 32; off; off >>= 1) v += __shfl_xor(v, off);
    v *= (1.0f / DD);
    float r = d0 * rsqrtf(v + EPSF);
    hout[i * DD + f] = r;
    hbf[i * DD + f] = f2bf_u(r);
}

// ---------------- B-stage, transposed orientation: m in regs, j in lanes ----------------
// grid 2048: fix = bid>>1, half = bid&1 (32 of 64 j-groups).
// D = A x B with A[m'][k] = h_fix[k]*W[k][mt*16+m'] (from LDS sW[m][k]),
// B[k][c] = hbf[g*16+c][k].  C: col=lane&15 = j, row=quad*4+reg -> m = mt*16+quad*4+reg.
// LN over m = per-lane sum of 16 regs + xor(16),xor(32).
__launch_bounds__(256)
__global__ void k_bstage(const float* __restrict__ h2, const unsigned short* __restrict__ hbf,
                         const float* __restrict__ WfT, const float* __restrict__ hbw,
                         const unsigned int* __restrict__ eim,
                         const unsigned int* __restrict__ eimT,
                         float* __restrict__ vp_part, float* __restrict__ vq_part) {
    int bid = blockIdx.x;
    int fix = bid >> 1, half = bid & 1;
    int tid = threadIdx.x;
    int lane = tid & 63, wave = tid >> 6;
    int l15 = lane & 15, quad = lane >> 4;

    __shared__ unsigned short sW[DD * SWP];
    __shared__ float red[4][2 * DD];

    {
        int m = tid >> 2;
        int k0 = (tid & 3) * 16;
        const float* hi = h2 + fix * DD;
        const float* wr = WfT + m * DD;
#pragma unroll
        for (int u = 0; u < 16; ++u) {
            int k = k0 + u;
            sW[m * SWP + k] = f2bf_u(hi[k] * wr[k]);
        }
    }
    __syncthreads();

    // A-frags (loop-invariant)
    short8 Af[4][2];
#pragma unroll
    for (int mt = 0; mt < 4; ++mt)
#pragma unroll
        for (int kt = 0; kt < 2; ++kt)
            Af[mt][kt] = *(const short8*)(sW + (mt * 16 + l15) * SWP + kt * 32 + quad * 8);

    // bias constants per lane: m = mt*16 + quad*4 + r
    float hb0[4][4], hww[4][4];
#pragma unroll
    for (int mt = 0; mt < 4; ++mt) {
        f32x4 a = *(const f32x4*)(hbw + mt * 16 + quad * 4);
        f32x4 wv = *(const f32x4*)(hbw + 64 + mt * 16 + quad * 4);
#pragma unroll
        for (int r = 0; r < 4; ++r) { hb0[mt][r] = a[r]; hww[mt][r] = wv[r]; }
    }

    float accf[4][4], accb[4][4];
#pragma unroll
    for (int mt = 0; mt < 4; ++mt)
#pragma unroll
        for (int r = 0; r < 4; ++r) { accf[mt][r] = 0.f; accb[mt][r] = 0.f; }

    for (int g = half * 32 + wave; g < half * 32 + 32; g += 4) {
        short8 B0 = *(const short8*)(hbf + (g * 16 + l15) * DD + quad * 8);
        short8 B1 = *(const short8*)(hbf + (g * 16 + l15) * DD + 32 + quad * 8);

        f32x4 C[4];
#pragma unroll
        for (int mt = 0; mt < 4; ++mt) C[mt] = (f32x4){0.f, 0.f, 0.f, 0.f};
#pragma unroll
        for (int mt = 0; mt < 4; ++mt)
            C[mt] = __builtin_amdgcn_mfma_f32_16x16x32_bf16(Af[mt][0], B0, C[mt], 0, 0, 0);
#pragma unroll
        for (int mt = 0; mt < 4; ++mt)
            C[mt] = __builtin_amdgcn_mfma_f32_16x16x32_bf16(Af[mt][1], B1, C[mt], 0, 0, 0);

        unsigned int base = (unsigned int)(fix * NN + g * 16);
        unsigned int sf = (eim[base >> 5] >> (base & 31)) & 0xFFFFu;
        unsigned int sb = (eimT[base >> 5] >> (base & 31)) & 0xFFFFu;
        float ef = (float)((sf >> l15) & 1u);

        // v = C + hb0 + ef*w  (in place; C dead after)
        float s1 = 0.f, s2 = 0.f;
#pragma unroll
        for (int mt = 0; mt < 4; ++mt)
#pragma unroll
            for (int r = 0; r < 4; ++r) {
                float v = C[mt][r] + hb0[mt][r] + ef * hww[mt][r];
                C[mt][r] = v;
                s1 += v;
                s2 += v * v;
            }
        s1 += __shfl_xor(s1, 16); s1 += __shfl_xor(s1, 32);
        s2 += __shfl_xor(s2, 16); s2 += __shfl_xor(s2, 32);
        float mean = s1 * (1.f / DD);
        float var = fmaxf(s2 * (1.f / DD) - mean * mean, 0.f);
        float rs = rsqrtf(var + EPSF);
        float mrs = mean * rs;

        if (sf == sb) {
#pragma unroll
            for (int mt = 0; mt < 4; ++mt)
#pragma unroll
                for (int r = 0; r < 4; ++r) {
                    float u = fmaxf(C[mt][r] * rs - mrs, 0.f);
                    accf[mt][r] += u;
                    accb[mt][r] += u;
                }
        } else {
#pragma unroll
            for (int mt = 0; mt < 4; ++mt)
#pragma unroll
                for (int r = 0; r < 4; ++r)
                    accf[mt][r] += fmaxf(C[mt][r] * rs - mrs, 0.f);
            float de = (float)((sb >> l15) & 1u) - ef;
            float t1 = 0.f, t2 = 0.f;
#pragma unroll
            for (int mt = 0; mt < 4; ++mt)
#pragma unroll
                for (int r = 0; r < 4; ++r) {
                    float v = C[mt][r] + de * hww[mt][r];
                    C[mt][r] = v;
                    t1 += v;
                    t2 += v * v;
                }
            t1 += __shfl_xor(t1, 16); t1 += __shfl_xor(t1, 32);
            t2 += __shfl_xor(t2, 16); t2 += __shfl_xor(t2, 32);
            float mean2 = t1 * (1.f / DD);
            float var2 = fmaxf(t2 * (1.f / DD) - mean2 * mean2, 0.f);
            float rs2 = rsqrtf(var2 + EPSF);
            float mrs2 = mean2 * rs2;
#pragma unroll
            for (int mt = 0; mt < 4; ++mt)
#pragma unroll
                for (int r = 0; r < 4; ++r)
                    accb[mt][r] += fmaxf(C[mt][r] * rs2 - mrs2, 0.f);
        }
    }

    // reduce over the 16 j-lanes (xor 1,2,4,8 stays within quad-group)
#pragma unroll
    for (int step = 1; step < 16; step <<= 1)
#pragma unroll
        for (int mt = 0; mt < 4; ++mt)
#pragma unroll
            for (int r = 0; r < 4; ++r) {
                accf[mt][r] += __shfl_xor(accf[mt][r], step);
                accb[mt][r] += __shfl_xor(accb[mt][r], step);
            }

    if (l15 == 0) {
#pragma unroll
        for (int mt = 0; mt < 4; ++mt)
#pragma unroll
            for (int r = 0; r < 4; ++r) {
                int m = mt * 16 + quad * 4 + r;
                red[wave][m] = accf[mt][r];
                red[wave][DD + m] = accb[mt][r];
            }
    }
    __syncthreads();
    if (tid < 2 * DD) {
        float sum = red[0][tid] + red[1][tid] + red[2][tid] + red[3][tid];
        if (tid < DD) vp_part[(half * NN + fix) * DD + tid] = sum;
        else          vq_part[(half * NN + fix) * DD + (tid - DD)] = sum;
    }
}

// ---------------- per-node projections (sums the two bstage partials) ----------------
__global__ void k_ppqq2(const float* __restrict__ vpp, const float* __restrict__ vqp,
                        const float* __restrict__ gWf,
                        float* __restrict__ ppb, float* __restrict__ qqb) {
    int b = blockIdx.x;
    int f = threadIdx.x;
    int i = b & 1023, which = b >> 10;
    const float* part = which ? vqp : vpp;
    int row0 = which ? 129 : 65;
    __shared__ float sv[DD];
    sv[f] = part[i * DD + f] + part[(NN + i) * DD + f];
    __syncthreads();
    float o = 0.f;
    for (int k = 0; k < DD; ++k) o += sv[k] * gWf[(row0 + k) * DD + f];
    (which ? qqb : ppb)[i * DD + f] = o;
}

// ---------------- final via MFMA: 128 blocks x 64 pairs ----------------
__launch_bounds__(256)
__global__ void k_final(const int* __restrict__ pos, const unsigned short* __restrict__ hbf,
                        const float* __restrict__ gWf, const unsigned int* __restrict__ eim,
                        const float* __restrict__ pp, const float* __restrict__ qq,
                        const float* __restrict__ linf, const int* __restrict__ flag,
                        void* __restrict__ outv) {
    int blk = blockIdx.x;
    int tid = threadIdx.x;
    int lane = tid & 63, wave = tid >> 6;
    int l15 = lane & 15, quad = lane >> 4;

    __shared__ unsigned short sgW[DD * SWP];   // [m][k] = bf16(g_W[k][m])
    __shared__ unsigned short sq[64 * SWP];    // [pair-in-block][k]

    {
        int m = tid >> 2;
        int k0 = (tid & 3) * 16;
#pragma unroll
        for (int u = 0; u < 16; ++u) {
            int k = k0 + u;
            sgW[m * SWP + k] = f2bf_u(gWf[k * DD + m]);
        }
    }
    for (int u = 0; u < 16; ++u) {
        int row = wave * 16 + u;
        int p = blk * 64 + row;
        int a = pos[2 * p], b = pos[2 * p + 1];
        float prod = bfu2f(hbf[a * DD + lane]) * bfu2f(hbf[b * DD + lane]);
        sq[row * SWP + lane] = f2bf_u(prod);
    }
    __syncthreads();

    short8 B0 = *(const short8*)(sq + (wave * 16 + l15) * SWP + quad * 8);
    short8 B1 = *(const short8*)(sq + (wave * 16 + l15) * SWP + 32 + quad * 8);

    f32x4 C[4];
#pragma unroll
    for (int mt = 0; mt < 4; ++mt) C[mt] = (f32x4){0.f, 0.f, 0.f, 0.f};
#pragma unroll
    for (int mt = 0; mt < 4; ++mt) {
        short8 A0 = *(const short8*)(sgW + (mt * 16 + l15) * SWP + quad * 8);
        C[mt] = __builtin_amdgcn_mfma_f32_16x16x32_bf16(A0, B0, C[mt], 0, 0, 0);
    }
#pragma unroll
    for (int mt = 0; mt < 4; ++mt) {
        short8 A1 = *(const short8*)(sgW + (mt * 16 + l15) * SWP + 32 + quad * 8);
        C[mt] = __builtin_amdgcn_mfma_f32_16x16x32_bf16(A1, B1, C[mt], 0, 0, 0);
    }

    // epilogue: lane's pair
    int p = blk * 64 + wave * 16 + l15;
    int a = pos[2 * p], b = pos[2 * p + 1];
    unsigned int iab = (unsigned int)(a * NN + b), iba = (unsigned int)(b * NN + a);
    float eab = (float)((eim[iab >> 5] >> (iab & 31)) & 1u);
    float eba = (float)((eim[iba >> 5] >> (iba & 31)) & 1u);

    float u1[4][4], u2[4][4];
    float s1 = 0.f, s12 = 0.f, s2 = 0.f, s22 = 0.f;
#pragma unroll
    for (int mt = 0; mt < 4; ++mt) {
        int m0 = mt * 16 + quad * 4;
        f32x4 w64v = *(const f32x4*)(gWf + 64 * DD + m0);
        f32x4 gbv  = *(const f32x4*)(gWf + 193 * DD + m0);
        f32x4 ppa  = *(const f32x4*)(pp + a * DD + m0);
        f32x4 qqb_ = *(const f32x4*)(qq + b * DD + m0);
        f32x4 ppb_ = *(const f32x4*)(pp + b * DD + m0);
        f32x4 qqa  = *(const f32x4*)(qq + a * DD + m0);
#pragma unroll
        for (int r = 0; r < 4; ++r) {
            float v1 = C[mt][r] + eab * w64v[r] + ppa[r] + qqb_[r] + gbv[r];
            float v2 = C[mt][r] + eba * w64v[r] + ppb_[r] + qqa[r] + gbv[r];
            u1[mt][r] = v1; u2[mt][r] = v2;
            s1 += v1; s12 += v1 * v1;
            s2 += v2; s22 += v2 * v2;
        }
    }
    s1 += __shfl_xor(s1, 16);  s1 += __shfl_xor(s1, 32);
    s12 += __shfl_xor(s12, 16); s12 += __shfl_xor(s12, 32);
    s2 += __shfl_xor(s2, 16);  s2 += __shfl_xor(s2, 32);
    s22 += __shfl_xor(s22, 16); s22 += __shfl_xor(s22, 32);
    float mean1 = s1 * (1.f / DD);
    float rs1 = rsqrtf(fmaxf(s12 * (1.f / DD) - mean1 * mean1, 0.f) + EPSF);
    float mrs1 = mean1 * rs1;
    float mean2 = s2 * (1.f / DD);
    float rs2 = rsqrtf(fmaxf(s22 * (1.f / DD) - mean2 * mean2, 0.f) + EPSF);
    float mrs2 = mean2 * rs2;

    float r = 0.f;
#pragma unroll
    for (int mt = 0; mt < 4; ++mt) {
        f32x4 lw = *(const f32x4*)(linf + mt * 16 + quad * 4);
#pragma unroll
        for (int rr = 0; rr < 4; ++rr) {
            float g1 = fmaxf(u1[mt][rr] * rs1 - mrs1, 0.f);
            float g2 = fmaxf(u2[mt][rr] * rs2 - mrs2, 0.f);
            r += g1 * g2 * lw[rr];
        }
    }
    r += __shfl_xor(r, 16); r += __shfl_xor(r, 32);
    if (quad == 0) {
        float res = r + linf[DD];
        if (*flag) ((float*)outv)[p] = res;
        else       ((bf16*)outv)[p] = __float2bfloat16(res);
    }
}

extern "C" void kernel_launch(void* const* d_in, const int* in_sizes, int n_in,
                              void* d_out, int out_size, void* d_ws, size_t ws_size,
                              hipStream_t stream) {
    const int* x      = (const int*)d_in[0];
    const int* ei     = (const int*)d_in[1];
    const int* pos    = (const int*)d_in[2];
    const void* emb     = d_in[3];
    const void* sage_Wl = d_in[4];
    const void* sage_bl = d_in[5];
    const void* sage_Wr = d_in[6];
    const void* h_W     = d_in[7];
    const void* h_b     = d_in[8];
    const void* g_W     = d_in[9];
    const void* g_b     = d_in[10];
    const void* lin_W   = d_in[11];
    const void* lin_b   = d_in[12];

    char* w = (char*)d_ws;
    auto alloc = [&](size_t bytes) {
        void* p = (void*)w;
        w += (bytes + 255) & ~(size_t)255;
        return p;
    };
    // ---- contiguous zero region ----
    int*   flag = (int*)alloc(256);
    int*   degi = (int*)alloc(NN * 4);
    unsigned int* eim  = (unsigned int*)alloc(NN * NN / 8);
    unsigned int* eimT = (unsigned int*)alloc(NN * NN / 8);
    size_t zero_bytes = (size_t)((char*)w - (char*)d_ws);
    // ---- rest ----
    float* h0   = (float*)alloc(NN * DD * 4);
    float* h1   = (float*)alloc(NN * DD * 4);
    float* h2   = (float*)alloc(NN * DD * 4);
    unsigned short* hbf = (unsigned short*)alloc(NN * DD * 2);
    float* Wlf  = (float*)alloc(2 * DD * DD * 4);
    float* blf  = (float*)alloc(2 * DD * 4);
    float* Wrf  = (float*)alloc(2 * DD * DD * 4);
    float* WfT  = (float*)alloc(DD * DD * 4);
    float* hbw  = (float*)alloc(128 * 4);
    float* gWf  = (float*)alloc(194 * DD * 4);
    float* linf = (float*)alloc(65 * 4);
    float* vpp  = (float*)alloc(2 * NN * DD * 4);
    float* vqp  = (float*)alloc(2 * NN * DD * 4);
    float* ppb  = (float*)alloc(NN * DD * 4);
    float* qqb  = (float*)alloc(NN * DD * 4);
    int* rowptr = (int*)alloc((NN + 1) * 4);
    int* cursor = (int*)alloc(NN * 4);
    int* csrc   = (int*)alloc(EE * 4);

    hipMemsetAsync(d_ws, 0, zero_bytes, stream);

    k_probe<<<(101 * DD + 255) / 256, 256, 0, stream>>>((const unsigned short*)emb, 101 * DD, flag);

    k_prep<<<452, 256, 0, stream>>>(emb, sage_Wl, sage_bl, sage_Wr, h_W, h_b, g_W, g_b,
                                    lin_W, lin_b, x, ei, flag,
                                    Wlf, blf, Wrf, WfT, hbw, gWf, linf,
                                    h0, degi, eim, eimT);

    k_scan<<<1, NN, 0, stream>>>(degi, rowptr, cursor);
    k_scatter<<<EE / 256, 256, 0, stream>>>(ei, cursor, csrc);

    // SAGE rounds (CSR-fused aggregation)
    k_sage<<<NN, DD, 0, stream>>>(rowptr, csrc, h0, Wlf, blf, Wrf, h1, hbf);
    k_sage<<<NN, DD, 0, stream>>>(rowptr, csrc, h1, Wlf + DD * DD, blf + DD,
                                  Wrf + DD * DD, h2, hbf);

    // B-stage (transposed MFMA orientation, 2 blocks/node)
    k_bstage<<<2 * NN, 256, 0, stream>>>(h2, hbf, WfT, hbw, eim, eimT, vpp, vqp);

    // per-node projections
    k_ppqq2<<<2 * NN, DD, 0, stream>>>(vpp, vqp, gWf, ppb, qqb);

    // final selected pairs (MFMA)
    k_final<<<PP / 64, 256, 0, stream>>>(pos, hbf, gWf, eim, ppb, qqb, linf, flag, d_out);
}

// Round 7
// 164.755 us; speedup vs baseline: 3.1037x; 1.0191x over previous
//
#include <hip/hip_runtime.h>
#include <hip/hip_bf16.h>
#include <hip/hip_cooperative_groups.h>

#define NN 1024
#define DD 64
#define EE 16384
#define PP 8192
#define EPSF 1e-5f
#define SWP (DD + 8)       // padded LDS row stride in shorts (144 B)
#define SMEM_BYTES 11264   // 9216 (sW) + 2048 (red) -- must stay <= 16384 for 4 blocks/CU

namespace cg = cooperative_groups;

typedef __hip_bfloat16 bf16;
typedef __attribute__((ext_vector_type(8))) short short8;
typedef __attribute__((ext_vector_type(4))) float f32x4;

static __device__ __forceinline__ float dec1(const void* src, int i, int fl) {
    if (fl) return ((const float*)src)[i];
    return __bfloat162float(((const bf16*)src)[i]);
}
static __device__ __forceinline__ unsigned short f2bf_u(float f) {
    bf16 h = __float2bfloat16(f);
    return *reinterpret_cast<unsigned short*>(&h);
}
static __device__ __forceinline__ float bfu2f(unsigned short u) {
    return __uint_as_float(((unsigned int)u) << 16);
}

struct P {
    const int *x, *ei, *pos;
    const void *emb, *sWl, *sbl, *sWr, *hW, *hb, *gW, *gb, *lW, *lb;
    float *Wlf, *blf, *Wrf, *WfT, *hbw, *gWf, *linf;
    float *h0, *h1, *h2;
    unsigned short *hbf;
    int *deg, *rowptr, *cursor, *csrc;
    unsigned int *eim, *eimT;
    float *vecp, *vecq, *ppb, *qqb;
    void *out;
};

static __device__ __forceinline__ int probe_fl(const void* emb) {
    int lane = threadIdx.x & 63;
    unsigned short raw = ((const unsigned short*)emb)[lane];
    float v = __uint_as_float(((unsigned int)raw) << 16);
    return (__ballot(!(fabsf(v) <= 1e3f)) != 0ull) ? 1 : 0;
}

// ---------------- phase 0: decodes + embed + deg/eim ----------------
static __device__ void phase_decode(const P& p, int b, int tid, int fl) {
    if (b < 32) { int i = b * 256 + tid; p.Wlf[i] = dec1(p.sWl, i, fl); }
    else if (b == 32) { if (tid < 128) p.blf[tid] = dec1(p.sbl, tid, fl); }
    else if (b < 65) { int i = (b - 33) * 256 + tid; p.Wrf[i] = dec1(p.sWr, i, fl); }
    else if (b < 82) {
        int i = (b - 65) * 256 + tid;
        if (i < 4096) { int n = i >> 6, k = i & 63; p.WfT[n * DD + k] = dec1(p.hW, k * DD + n, fl); }
        else if (i < 4160) p.hbw[i - 4096] = dec1(p.hb, i - 4096, fl);
        else if (i < 4224) p.hbw[64 + (i - 4160)] = dec1(p.hW, 64 * DD + (i - 4160), fl);
    } else if (b < 131) {
        int i = (b - 82) * 256 + tid;
        if (i < 193 * DD) p.gWf[i] = dec1(p.gW, i, fl);
        else if (i < 194 * DD) p.gWf[i] = dec1(p.gb, i - 193 * DD, fl);
    } else if (b == 131) {
        if (tid < DD) p.linf[tid] = dec1(p.lW, tid, fl);
        else if (tid == DD) p.linf[DD] = dec1(p.lb, 0, fl);
    } else if (b < 388) {
        int i = (b - 132) * 256 + tid;
        int node = i >> 6, f = i & 63;
        p.h0[i] = dec1(p.emb, p.x[node] * DD + f, fl);
    } else if (b < 452) {
        int e = (b - 388) * 256 + tid;
        int s = p.ei[e], d = p.ei[EE + e];
        atomicAdd(&p.deg[d], 1);
        unsigned int idx = (unsigned int)(s * NN + d);
        atomicOr(&p.eim[idx >> 5], 1u << (idx & 31));
        unsigned int idxT = (unsigned int)(d * NN + s);
        atomicOr(&p.eimT[idxT >> 5], 1u << (idxT & 31));
    }
}

// ---------------- phase 1: prefix scan (block 0 only) ----------------
static __device__ void phase_scan(const P& p, int b, int tid, char* smem) {
    if (b != 0) return;
    int* tmp = (int*)smem;
    int v[4]; int s = 0;
    int base4 = tid * 4;
#pragma unroll
    for (int u = 0; u < 4; ++u) { v[u] = p.deg[base4 + u]; s += v[u]; }
    tmp[tid] = s;
    __syncthreads();
    for (int off = 1; off < 256; off <<= 1) {
        int a = (tid >= off) ? tmp[tid - off] : 0;
        __syncthreads();
        tmp[tid] += a;
        __syncthreads();
    }
    int run = tmp[tid] - s;
#pragma unroll
    for (int u = 0; u < 4; ++u) {
        p.rowptr[base4 + u] = run;
        p.cursor[base4 + u] = run;
        run += v[u];
    }
    if (tid == 255) p.rowptr[NN] = run;
}

// ---------------- phase 2: scatter edges into CSR ----------------
static __device__ void phase_scatter(const P& p, int b, int tid) {
    if (b >= 64) return;
    int e = b * 256 + tid;
    int d = p.ei[EE + e];
    int c = atomicAdd(&p.cursor[d], 1);
    p.csrc[c] = p.ei[e];
}

// ---------------- phases 3/4: SAGE rounds (one wave per node) ----------------
static __device__ void phase_sage(const P& p, int b, int tid, char* smem, int round) {
    if (b >= 256) return;
    int lane = tid & 63, wave = tid >> 6;
    int node = b * 4 + wave;
    const float* hin = round ? p.h1 : p.h0;
    const float* Wl = p.Wlf + round * DD * DD;
    const float* bl = p.blf + round * DD;
    const float* Wr = p.Wrf + round * DD * DD;
    float* hout = round ? p.h2 : p.h1;

    float* sa = (float*)smem + wave * 2 * DD;
    float* sh = sa + DD;
    int r0 = p.rowptr[node], r1 = p.rowptr[node + 1];
    float s = 0.f;
    for (int r = r0; r < r1; ++r) s += hin[p.csrc[r] * DD + lane];
    sa[lane] = s / (float)max(r1 - r0, 1);
    sh[lane] = hin[node * DD + lane];
    float o = bl[lane];
    for (int k = 0; k < DD; ++k)
        o += sa[k] * Wl[k * DD + lane] + sh[k] * Wr[k * DD + lane];
    float m = o;
    for (int off = 32; off; off >>= 1) m += __shfl_xor(m, off);
    m *= (1.f / DD);
    float d0 = o - m;
    float v = d0 * d0;
    for (int off = 32; off; off >>= 1) v += __shfl_xor(v, off);
    v *= (1.f / DD);
    float r = d0 * rsqrtf(v + EPSF);
    hout[node * DD + lane] = r;
    if (round) p.hbf[node * DD + lane] = f2bf_u(r);
}

// ---------------- phase 5: B-stage (MFMA), one node per block ----------------
static __device__ void phase_bstage(const P& p, int b, int tid, char* smem) {
    int lane = tid & 63, wave = tid >> 6;
    int l15 = lane & 15, quad = lane >> 4;
    unsigned short* sW = (unsigned short*)smem;          // DD*SWP shorts = 9216 B
    float* red = (float*)(smem + DD * SWP * 2);          // 4*128 floats = 2048 B
    {
        int m = tid >> 2;
        int k0 = (tid & 3) * 16;
        const float* hi = p.h2 + b * DD;
        const float* wr = p.WfT + m * DD;
        unsigned short tmp[16];
#pragma unroll
        for (int u = 0; u < 16; ++u) tmp[u] = f2bf_u(hi[k0 + u] * wr[k0 + u]);
        *(short8*)(sW + m * SWP + k0) = *(short8*)tmp;
        *(short8*)(sW + m * SWP + k0 + 8) = *(short8*)(tmp + 8);
    }
    __syncthreads();

    short8 Af[4][2];
#pragma unroll
    for (int mt = 0; mt < 4; ++mt)
#pragma unroll
        for (int kt = 0; kt < 2; ++kt)
            Af[mt][kt] = *(const short8*)(sW + (mt * 16 + l15) * SWP + kt * 32 + quad * 8);

    float hb0[4][4], hww[4][4];
#pragma unroll
    for (int mt = 0; mt < 4; ++mt) {
        f32x4 a = *(const f32x4*)(p.hbw + mt * 16 + quad * 4);
        f32x4 wv = *(const f32x4*)(p.hbw + 64 + mt * 16 + quad * 4);
#pragma unroll
        for (int r = 0; r < 4; ++r) { hb0[mt][r] = a[r]; hww[mt][r] = wv[r]; }
    }

    float accf[4][4], accb[4][4];
#pragma unroll
    for (int mt = 0; mt < 4; ++mt)
#pragma unroll
        for (int r = 0; r < 4; ++r) { accf[mt][r] = 0.f; accb[mt][r] = 0.f; }

    int g = wave;
    short8 B0 = *(const short8*)(p.hbf + (g * 16 + l15) * DD + quad * 8);
    short8 B1 = *(const short8*)(p.hbf + (g * 16 + l15) * DD + 32 + quad * 8);

    for (int it = 0; it < 16; ++it, g += 4) {
        short8 cB0 = B0, cB1 = B1;
        if (it < 15) {
            int gn = g + 4;
            B0 = *(const short8*)(p.hbf + (gn * 16 + l15) * DD + quad * 8);
            B1 = *(const short8*)(p.hbf + (gn * 16 + l15) * DD + 32 + quad * 8);
        }
        unsigned int base = (unsigned int)(b * NN + g * 16);
        unsigned int sf = (p.eim[base >> 5] >> (base & 31)) & 0xFFFFu;
        unsigned int sb = (p.eimT[base >> 5] >> (base & 31)) & 0xFFFFu;

        f32x4 C[4];
#pragma unroll
        for (int mt = 0; mt < 4; ++mt)
            C[mt] = (f32x4){hb0[mt][0], hb0[mt][1], hb0[mt][2], hb0[mt][3]};
#pragma unroll
        for (int mt = 0; mt < 4; ++mt)
            C[mt] = __builtin_amdgcn_mfma_f32_16x16x32_bf16(Af[mt][0], cB0, C[mt], 0, 0, 0);
#pragma unroll
        for (int mt = 0; mt < 4; ++mt)
            C[mt] = __builtin_amdgcn_mfma_f32_16x16x32_bf16(Af[mt][1], cB1, C[mt], 0, 0, 0);

        float ef = (float)((sf >> l15) & 1u);
        float s1 = 0.f, s2 = 0.f;
#pragma unroll
        for (int mt = 0; mt < 4; ++mt)
#pragma unroll
            for (int r = 0; r < 4; ++r) {
                float v = C[mt][r] + ef * hww[mt][r];
                C[mt][r] = v;
                s1 += v;
                s2 += v * v;
            }
        s1 += __shfl_xor(s1, 16); s1 += __shfl_xor(s1, 32);
        s2 += __shfl_xor(s2, 16); s2 += __shfl_xor(s2, 32);
        float mean = s1 * (1.f / DD);
        float var = fmaxf(s2 * (1.f / DD) - mean * mean, 0.f);
        float rs = rsqrtf(var + EPSF);
        float mrs = mean * rs;

        if (sf == sb) {
#pragma unroll
            for (int mt = 0; mt < 4; ++mt)
#pragma unroll
                for (int r = 0; r < 4; ++r) {
                    float u = fmaxf(C[mt][r] * rs - mrs, 0.f);
                    accf[mt][r] += u;
                    accb[mt][r] += u;
                }
        } else {
#pragma unroll
            for (int mt = 0; mt < 4; ++mt)
#pragma unroll
                for (int r = 0; r < 4; ++r)
                    accf[mt][r] += fmaxf(C[mt][r] * rs - mrs, 0.f);
            float de = (float)((sb >> l15) & 1u) - ef;
            float t1 = 0.f, t2 = 0.f;
#pragma unroll
            for (int mt = 0; mt < 4; ++mt)
#pragma unroll
                for (int r = 0; r < 4; ++r) {
                    float v = C[mt][r] + de * hww[mt][r];
                    C[mt][r] = v;
                    t1 += v;
                    t2 += v * v;
                }
            t1 += __shfl_xor(t1, 16); t1 += __shfl_xor(t1, 32);
            t2 += __shfl_xor(t2, 16); t2 += __shfl_xor(t2, 32);
            float mean2 = t1 * (1.f / DD);
            float var2 = fmaxf(t2 * (1.f / DD) - mean2 * mean2, 0.f);
            float rs2 = rsqrtf(var2 + EPSF);
            float mrs2 = mean2 * rs2;
#pragma unroll
            for (int mt = 0; mt < 4; ++mt)
#pragma unroll
                for (int r = 0; r < 4; ++r)
                    accb[mt][r] += fmaxf(C[mt][r] * rs2 - mrs2, 0.f);
        }
    }

#pragma unroll
    for (int step = 1; step < 16; step <<= 1)
#pragma unroll
        for (int mt = 0; mt < 4; ++mt)
#pragma unroll
            for (int r = 0; r < 4; ++r) {
                accf[mt][r] += __shfl_xor(accf[mt][r], step);
                accb[mt][r] += __shfl_xor(accb[mt][r], step);
            }
    if (l15 == 0) {
#pragma unroll
        for (int mt = 0; mt < 4; ++mt)
#pragma unroll
            for (int r = 0; r < 4; ++r) {
                int m = mt * 16 + quad * 4 + r;
                red[wave * 128 + m] = accf[mt][r];
                red[wave * 128 + DD + m] = accb[mt][r];
            }
    }
    __syncthreads();
    if (tid < 2 * DD) {
        float sum = red[tid] + red[128 + tid] + red[256 + tid] + red[384 + tid];
        if (tid < DD) p.vecp[b * DD + tid] = sum;
        else          p.vecq[b * DD + (tid - DD)] = sum;
    }
}

// ---------------- phase 6: per-node projections ----------------
static __device__ void phase_ppqq(const P& p, int b, int tid, char* smem) {
    int lane = tid & 63, wave = tid >> 6;
    if (wave >= 2) return;
    int unit = b * 2 + wave;
    int i = unit & 1023, which = unit >> 10;
    int row0 = which ? 129 : 65;
    float* sv = (float*)smem + wave * DD;
    sv[lane] = (which ? p.vecq : p.vecp)[i * DD + lane];
    float o = 0.f;
    for (int k = 0; k < DD; ++k) o += sv[k] * p.gWf[(row0 + k) * DD + lane];
    (which ? p.qqb : p.ppb)[i * DD + lane] = o;
}

// ---------------- phase 7: final selected pairs (MFMA; B-frag in registers) ----------------
static __device__ void phase_final(const P& p, int b, int tid, int fl, char* smem) {
    if (b >= PP / 64) return;
    int lane = tid & 63, wave = tid >> 6;
    int l15 = lane & 15, quad = lane >> 4;
    unsigned short* sgW = (unsigned short*)smem;   // DD*SWP shorts = 9216 B
    {
        int m = tid >> 2;
        int k0 = (tid & 3) * 16;
        unsigned short tmp[16];
#pragma unroll
        for (int u = 0; u < 16; ++u) tmp[u] = f2bf_u(p.gWf[(k0 + u) * DD + m]);
        *(short8*)(sgW + m * SWP + k0) = *(short8*)tmp;
        *(short8*)(sgW + m * SWP + k0 + 8) = *(short8*)(tmp + 8);
    }

    // this lane's pair: build B-frags in registers (no LDS staging)
    int pp_ = b * 64 + wave * 16 + l15;
    int a = p.pos[2 * pp_], bb = p.pos[2 * pp_ + 1];
    short8 ha0 = *(const short8*)(p.hbf + a * DD + quad * 8);
    short8 hb0v = *(const short8*)(p.hbf + bb * DD + quad * 8);
    short8 ha1 = *(const short8*)(p.hbf + a * DD + 32 + quad * 8);
    short8 hb1v = *(const short8*)(p.hbf + bb * DD + 32 + quad * 8);
    short8 B0, B1;
#pragma unroll
    for (int j = 0; j < 8; ++j) {
        B0[j] = (short)f2bf_u(bfu2f((unsigned short)ha0[j]) * bfu2f((unsigned short)hb0v[j]));
        B1[j] = (short)f2bf_u(bfu2f((unsigned short)ha1[j]) * bfu2f((unsigned short)hb1v[j]));
    }
    __syncthreads();

    f32x4 C[4];
#pragma unroll
    for (int mt = 0; mt < 4; ++mt) C[mt] = (f32x4){0.f, 0.f, 0.f, 0.f};
#pragma unroll
    for (int mt = 0; mt < 4; ++mt) {
        short8 A0 = *(const short8*)(sgW + (mt * 16 + l15) * SWP + quad * 8);
        C[mt] = __builtin_amdgcn_mfma_f32_16x16x32_bf16(A0, B0, C[mt], 0, 0, 0);
    }
#pragma unroll
    for (int mt = 0; mt < 4; ++mt) {
        short8 A1 = *(const short8*)(sgW + (mt * 16 + l15) * SWP + 32 + quad * 8);
        C[mt] = __builtin_amdgcn_mfma_f32_16x16x32_bf16(A1, B1, C[mt], 0, 0, 0);
    }

    unsigned int iab = (unsigned int)(a * NN + bb), iba = (unsigned int)(bb * NN + a);
    float eab = (float)((p.eim[iab >> 5] >> (iab & 31)) & 1u);
    float eba = (float)((p.eim[iba >> 5] >> (iba & 31)) & 1u);

    float u1[4][4], u2[4][4];
    float s1 = 0.f, s12 = 0.f, s2 = 0.f, s22 = 0.f;
#pragma unroll
    for (int mt = 0; mt < 4; ++mt) {
        int m0 = mt * 16 + quad * 4;
        f32x4 w64v = *(const f32x4*)(p.gWf + 64 * DD + m0);
        f32x4 gbv  = *(const f32x4*)(p.gWf + 193 * DD + m0);
        f32x4 ppa  = *(const f32x4*)(p.ppb + a * DD + m0);
        f32x4 qqb_ = *(const f32x4*)(p.qqb + bb * DD + m0);
        f32x4 ppb_ = *(const f32x4*)(p.ppb + bb * DD + m0);
        f32x4 qqa  = *(const f32x4*)(p.qqb + a * DD + m0);
#pragma unroll
        for (int r = 0; r < 4; ++r) {
            float v1 = C[mt][r] + eab * w64v[r] + ppa[r] + qqb_[r] + gbv[r];
            float v2 = C[mt][r] + eba * w64v[r] + ppb_[r] + qqa[r] + gbv[r];
            u1[mt][r] = v1; u2[mt][r] = v2;
            s1 += v1; s12 += v1 * v1;
            s2 += v2; s22 += v2 * v2;
        }
    }
    s1 += __shfl_xor(s1, 16);  s1 += __shfl_xor(s1, 32);
    s12 += __shfl_xor(s12, 16); s12 += __shfl_xor(s12, 32);
    s2 += __shfl_xor(s2, 16);  s2 += __shfl_xor(s2, 32);
    s22 += __shfl_xor(s22, 16); s22 += __shfl_xor(s22, 32);
    float mean1 = s1 * (1.f / DD);
    float rs1 = rsqrtf(fmaxf(s12 * (1.f / DD) - mean1 * mean1, 0.f) + EPSF);
    float mrs1 = mean1 * rs1;
    float mean2 = s2 * (1.f / DD);
    float rs2 = rsqrtf(fmaxf(s22 * (1.f / DD) - mean2 * mean2, 0.f) + EPSF);
    float mrs2 = mean2 * rs2;

    float r = 0.f;
#pragma unroll
    for (int mt = 0; mt < 4; ++mt) {
        f32x4 lw = *(const f32x4*)(p.linf + mt * 16 + quad * 4);
#pragma unroll
        for (int rr = 0; rr < 4; ++rr) {
            float g1 = fmaxf(u1[mt][rr] * rs1 - mrs1, 0.f);
            float g2 = fmaxf(u2[mt][rr] * rs2 - mrs2, 0.f);
            r += g1 * g2 * lw[rr];
        }
    }
    r += __shfl_xor(r, 16); r += __shfl_xor(r, 32);
    if (quad == 0) {
        float res = r + p.linf[DD];
        if (fl) ((float*)p.out)[pp_] = res;
        else    ((bf16*)p.out)[pp_] = __float2bfloat16(res);
    }
}

// ---------------- cooperative mega-kernel ----------------
__global__ __launch_bounds__(256, 4) void k_all(P p) {
    cg::grid_group gg = cg::this_grid();
    __shared__ __align__(16) char smem[SMEM_BYTES];
    const int tid = threadIdx.x, b = blockIdx.x;
    int fl = probe_fl(p.emb);

    phase_decode(p, b, tid, fl);   gg.sync();
    phase_scan(p, b, tid, smem);   gg.sync();
    phase_scatter(p, b, tid);      gg.sync();
    phase_sage(p, b, tid, smem, 0); gg.sync();
    phase_sage(p, b, tid, smem, 1); gg.sync();
    phase_bstage(p, b, tid, smem); gg.sync();
    phase_ppqq(p, b, tid, smem);   gg.sync();
    phase_final(p, b, tid, fl, smem);
}

// ---------------- fallback: one phase per ordinary launch ----------------
__global__ __launch_bounds__(256) void k_phase(P p, int phase) {
    __shared__ __align__(16) char smem[SMEM_BYTES];
    const int tid = threadIdx.x, b = blockIdx.x;
    int fl = probe_fl(p.emb);
    switch (phase) {
        case 0: phase_decode(p, b, tid, fl); break;
        case 1: phase_scan(p, b, tid, smem); break;
        case 2: phase_scatter(p, b, tid); break;
        case 3: phase_sage(p, b, tid, smem, 0); break;
        case 4: phase_sage(p, b, tid, smem, 1); break;
        case 5: phase_bstage(p, b, tid, smem); break;
        case 6: phase_ppqq(p, b, tid, smem); break;
        case 7: phase_final(p, b, tid, fl, smem); break;
    }
}

extern "C" void kernel_launch(void* const* d_in, const int* in_sizes, int n_in,
                              void* d_out, int out_size, void* d_ws, size_t ws_size,
                              hipStream_t stream) {
    char* w = (char*)d_ws;
    auto alloc = [&](size_t bytes) {
        void* q = (void*)w;
        w += (bytes + 255) & ~(size_t)255;
        return q;
    };
    // ---- contiguous zero region ----
    int* deg = (int*)alloc(NN * 4);
    unsigned int* eim  = (unsigned int*)alloc(NN * NN / 8);
    unsigned int* eimT = (unsigned int*)alloc(NN * NN / 8);
    size_t zero_bytes = (size_t)(w - (char*)d_ws);
    // ---- rest ----
    float* h0   = (float*)alloc(NN * DD * 4);
    float* h1   = (float*)alloc(NN * DD * 4);
    float* h2   = (float*)alloc(NN * DD * 4);
    unsigned short* hbf = (unsigned short*)alloc(NN * DD * 2);
    float* Wlf  = (float*)alloc(2 * DD * DD * 4);
    float* blf  = (float*)alloc(2 * DD * 4);
    float* Wrf  = (float*)alloc(2 * DD * DD * 4);
    float* WfT  = (float*)alloc(DD * DD * 4);
    float* hbw  = (float*)alloc(128 * 4);
    float* gWf  = (float*)alloc(194 * DD * 4);
    float* linf = (float*)alloc(65 * 4);
    float* vecp = (float*)alloc(NN * DD * 4);
    float* vecq = (float*)alloc(NN * DD * 4);
    float* ppb  = (float*)alloc(NN * DD * 4);
    float* qqb  = (float*)alloc(NN * DD * 4);
    int* rowptr = (int*)alloc((NN + 1) * 4);
    int* cursor = (int*)alloc(NN * 4);
    int* csrc   = (int*)alloc(EE * 4);

    hipMemsetAsync(d_ws, 0, zero_bytes, stream);

    P hp;
    hp.x = (const int*)d_in[0];
    hp.ei = (const int*)d_in[1];
    hp.pos = (const int*)d_in[2];
    hp.emb = d_in[3];
    hp.sWl = d_in[4];
    hp.sbl = d_in[5];
    hp.sWr = d_in[6];
    hp.hW = d_in[7];
    hp.hb = d_in[8];
    hp.gW = d_in[9];
    hp.gb = d_in[10];
    hp.lW = d_in[11];
    hp.lb = d_in[12];
    hp.Wlf = Wlf; hp.blf = blf; hp.Wrf = Wrf; hp.WfT = WfT; hp.hbw = hbw;
    hp.gWf = gWf; hp.linf = linf;
    hp.h0 = h0; hp.h1 = h1; hp.h2 = h2; hp.hbf = hbf;
    hp.deg = deg; hp.rowptr = rowptr; hp.cursor = cursor; hp.csrc = csrc;
    hp.eim = eim; hp.eimT = eimT;
    hp.vecp = vecp; hp.vecq = vecq; hp.ppb = ppb; hp.qqb = qqb;
    hp.out = d_out;

    // host-side feasibility gate (capture-safe host queries), then cooperative launch
    hipError_t err = hipErrorUnknown;
    int nb = 0, ncu = 0;
    if (hipOccupancyMaxActiveBlocksPerMultiprocessor(&nb, k_all, 256, 0) == hipSuccess &&
        hipDeviceGetAttribute(&ncu, hipDeviceAttributeMultiprocessorCount, 0) == hipSuccess &&
        (long)nb * ncu >= 1024) {
        void* args[] = { &hp };
        err = hipLaunchCooperativeKernel(k_all, dim3(1024), dim3(256), args, 0, stream);
    }
    if (err != hipSuccess) {
        // fallback: same phases as ordinary kernels
        k_phase<<<452, 256, 0, stream>>>(hp, 0);
        k_phase<<<1,   256, 0, stream>>>(hp, 1);
        k_phase<<<64,  256, 0, stream>>>(hp, 2);
        k_phase<<<256, 256, 0, stream>>>(hp, 3);
        k_phase<<<256, 256, 0, stream>>>(hp, 4);
        k_phase<<<1024, 256, 0, stream>>>(hp, 5);
        k_phase<<<1024, 256, 0, stream>>>(hp, 6);
        k_phase<<<128, 256, 0, stream>>>(hp, 7);
    }
}